// Round 1
// baseline (498.781 us; speedup 1.0000x reference)
//
#include <hip/hip_runtime.h>
#include <math.h>

#define N_NODES 20000
#define E_EDGES 640000
#define ET (E_EDGES + N_NODES)   // edges + self loops
#define IN_CH 256
#define D1 128                   // H1*C1 = 8*16
#define D2 256                   // H2*C2 = 1*256
#define BPAIRS 4096
#define NEG 0.2f

// ---------------- CSR build ----------------

__global__ void hist_kernel(const int* __restrict__ edge_dst,
                            int* __restrict__ count, int* __restrict__ rank) {
    int e = blockIdx.x * blockDim.x + threadIdx.x;
    if (e >= ET) return;
    int dst = (e < E_EDGES) ? edge_dst[e] : (e - E_EDGES);
    rank[e] = atomicAdd(&count[dst], 1);
}

// single-block exclusive scan of count[0..N) -> offsets[0..N]
__global__ __launch_bounds__(1024) void scan_kernel(const int* __restrict__ count,
                                                    int* __restrict__ offsets) {
    const int PER = (N_NODES + 1023) / 1024;   // 20
    int t = threadIdx.x;
    int base = t * PER;
    int local[PER];
    int sum = 0;
#pragma unroll
    for (int i = 0; i < PER; i++) {
        int idx = base + i;
        int v = (idx < N_NODES) ? count[idx] : 0;
        local[i] = sum;          // thread-local exclusive prefix
        sum += v;
    }
    int lane = t & 63, wave = t >> 6;
    int s = sum;
#pragma unroll
    for (int off = 1; off < 64; off <<= 1) {
        int x = __shfl_up(s, off);
        if (lane >= off) s += x;
    }
    __shared__ int wsum[16];
    __shared__ int wpre[16];
    if (lane == 63) wsum[wave] = s;
    __syncthreads();
    if (t == 0) {
        int acc = 0;
        for (int w = 0; w < 16; w++) { wpre[w] = acc; acc += wsum[w]; }
        offsets[N_NODES] = acc;  // == ET
    }
    __syncthreads();
    int thread_excl = wpre[wave] + (s - sum);
#pragma unroll
    for (int i = 0; i < PER; i++) {
        int idx = base + i;
        if (idx < N_NODES) offsets[idx] = thread_excl + local[i];
    }
}

__global__ void scatter_kernel(const int* __restrict__ edge_src,
                               const int* __restrict__ edge_dst,
                               const int* __restrict__ rank,
                               const int* __restrict__ offsets,
                               int* __restrict__ sorted_src) {
    int e = blockIdx.x * blockDim.x + threadIdx.x;
    if (e >= ET) return;
    int dst = (e < E_EDGES) ? edge_dst[e] : (e - E_EDGES);
    int src = (e < E_EDGES) ? edge_src[e] : (e - E_EDGES);
    sorted_src[offsets[dst] + rank[e]] = src;
}

// ---------------- dual GEMM: yl = x@Wl+bl, yr = x@Wr+br ----------------
// block = 2*MOUT threads, each block does ROWS rows. W row-major [K, MOUT].

template <int K, int MOUT, int ROWS>
__global__ __launch_bounds__(512) void dual_gemm_kernel(
        const float* __restrict__ x,
        const float* __restrict__ Wl, const float* __restrict__ bl,
        const float* __restrict__ Wr, const float* __restrict__ br,
        float* __restrict__ yl, float* __restrict__ yr, int n) {
    __shared__ float xs[ROWS * K];
    int row0 = blockIdx.x * ROWS;
    for (int idx = threadIdx.x; idx < ROWS * K; idx += blockDim.x) {
        int r = idx / K, k = idx - r * K;
        int row = row0 + r;
        xs[idx] = (row < n) ? x[row * K + k] : 0.f;
    }
    __syncthreads();

    int j = threadIdx.x;
    bool is_r = (j >= MOUT);
    int col = is_r ? j - MOUT : j;
    const float* W = is_r ? Wr : Wl;
    float bias = is_r ? br[col] : bl[col];

    float acc[ROWS];
#pragma unroll
    for (int r = 0; r < ROWS; r++) acc[r] = 0.f;

    const float4* xs4 = (const float4*)xs;
    for (int k4 = 0; k4 < K / 4; k4++) {
        int kk = k4 * 4;
        float w0 = W[(kk + 0) * MOUT + col];
        float w1 = W[(kk + 1) * MOUT + col];
        float w2 = W[(kk + 2) * MOUT + col];
        float w3 = W[(kk + 3) * MOUT + col];
#pragma unroll
        for (int r = 0; r < ROWS; r++) {
            float4 xv = xs4[r * (K / 4) + k4];
            acc[r] += xv.x * w0 + xv.y * w1 + xv.z * w2 + xv.w * w3;
        }
    }
    float* y = is_r ? yr : yl;
#pragma unroll
    for (int r = 0; r < ROWS; r++) {
        int row = row0 + r;
        if (row < n) y[row * MOUT + col] = acc[r] + bias;
    }
}

// ---------------- layer 1 aggregation (8 heads x 16 ch), online softmax ----------------
// one block (128 threads = 2 waves) per dst node; thread t -> (h = t>>4, c = t&15)

__global__ __launch_bounds__(128) void aggregate1_kernel(
        const float* __restrict__ xl1, const float* __restrict__ xr1,
        const float* __restrict__ att1, const float* __restrict__ bias1,
        const int* __restrict__ offsets, const int* __restrict__ sorted_src,
        float* __restrict__ x1) {
    int dst = blockIdx.x;
    int t = threadIdx.x;
    float xr = xr1[dst * D1 + t];
    float att = att1[t];
    float bias = bias1[t];
    int beg = offsets[dst], end = offsets[dst + 1];

    float m = -INFINITY, l = 0.f, acc = 0.f;
    for (int i = beg; i < end; i++) {
        int src = sorted_src[i];
        float v = xl1[src * D1 + t];
        float s = v + xr;
        float lr = (s > 0.f) ? s : NEG * s;
        float p = att * lr;
        // reduce over the 16 lanes of this head
        p += __shfl_xor(p, 1);
        p += __shfl_xor(p, 2);
        p += __shfl_xor(p, 4);
        p += __shfl_xor(p, 8);
        float e = p;
        float mnew = fmaxf(m, e);
        float corr = __expf(m - mnew);   // expf(-inf)=0 on first edge
        float pe = __expf(e - mnew);
        l = l * corr + pe;
        acc = acc * corr + pe * v;
        m = mnew;
    }
    // out + bias1, then relu (input to layer 2)
    x1[dst * D1 + t] = fmaxf(acc / l + bias, 0.f);
}

// ---------------- layer 2 aggregation (1 head x 256 ch) ----------------
// one wave per dst node; lane handles channels [lane*4, lane*4+4)

__device__ __forceinline__ float lrelu(float s) { return (s > 0.f) ? s : NEG * s; }

__global__ __launch_bounds__(256) void aggregate2_kernel(
        const float* __restrict__ xl2, const float* __restrict__ xr2,
        const float* __restrict__ att2, const float* __restrict__ bias2,
        const int* __restrict__ offsets, const int* __restrict__ sorted_src,
        float* __restrict__ x2) {
    int wave = threadIdx.x >> 6;
    int lane = threadIdx.x & 63;
    int dst = blockIdx.x * 4 + wave;
    if (dst >= N_NODES) return;

    float4 xr = ((const float4*)(xr2 + dst * D2))[lane];
    float4 att = ((const float4*)att2)[lane];
    int beg = offsets[dst], end = offsets[dst + 1];

    float m = -INFINITY, l = 0.f;
    float4 acc = {0.f, 0.f, 0.f, 0.f};
    for (int i = beg; i < end; i++) {
        int src = sorted_src[i];
        float4 v = ((const float4*)(xl2 + src * D2))[lane];
        float p = att.x * lrelu(v.x + xr.x) + att.y * lrelu(v.y + xr.y)
                + att.z * lrelu(v.z + xr.z) + att.w * lrelu(v.w + xr.w);
        p += __shfl_xor(p, 1);
        p += __shfl_xor(p, 2);
        p += __shfl_xor(p, 4);
        p += __shfl_xor(p, 8);
        p += __shfl_xor(p, 16);
        p += __shfl_xor(p, 32);
        float e = p;
        float mnew = fmaxf(m, e);
        float corr = __expf(m - mnew);
        float pe = __expf(e - mnew);
        l = l * corr + pe;
        acc.x = acc.x * corr + pe * v.x;
        acc.y = acc.y * corr + pe * v.y;
        acc.z = acc.z * corr + pe * v.z;
        acc.w = acc.w * corr + pe * v.w;
        m = mnew;
    }
    float4 bb = ((const float4*)bias2)[lane];
    float4 o;
    float inv_l = 1.f / l;
    o.x = acc.x * inv_l + bb.x;
    o.y = acc.y * inv_l + bb.y;
    o.z = acc.z * inv_l + bb.z;
    o.w = acc.w * inv_l + bb.w;
    ((float4*)(x2 + dst * D2))[lane] = o;
}

// ---------------- classifier ----------------
// logits[b] = [vx[a1], vx[a2], x2[a1], x2[a2]] . Wc + bc

__global__ __launch_bounds__(256) void classifier_kernel(
        const float* __restrict__ vanilla_x, const float* __restrict__ x2,
        const int* __restrict__ a1_raw, const int* __restrict__ a2_raw,
        const float* __restrict__ Wc, const float* __restrict__ bc,
        float* __restrict__ out) {
    int b = blockIdx.x;
    int t = threadIdx.x;

    // detect int64 vs int32 storage of index arrays (values < 2^31, so int64
    // layout has zero high words at every odd int32 position)
    __shared__ int stride_s;
    if (t == 0) {
        bool i64 = true;
        for (int i = 1; i < 63; i += 2) i64 = i64 && (a1_raw[i] == 0);
        stride_s = i64 ? 2 : 1;
    }
    __syncthreads();
    int stride = stride_s;
    int a1 = a1_raw[(long)b * stride];
    int a2 = a2_raw[(long)b * stride];

    float s = vanilla_x[a1 * IN_CH + t] * Wc[t]
            + vanilla_x[a2 * IN_CH + t] * Wc[IN_CH + t]
            + x2[a1 * D2 + t] * Wc[2 * IN_CH + t]
            + x2[a2 * D2 + t] * Wc[3 * IN_CH + t];
    s += __shfl_xor(s, 1);
    s += __shfl_xor(s, 2);
    s += __shfl_xor(s, 4);
    s += __shfl_xor(s, 8);
    s += __shfl_xor(s, 16);
    s += __shfl_xor(s, 32);
    __shared__ float part[4];
    if ((t & 63) == 0) part[t >> 6] = s;
    __syncthreads();
    if (t == 0) out[b] = part[0] + part[1] + part[2] + part[3] + bc[0];
}

// ---------------- launch ----------------

extern "C" void kernel_launch(void* const* d_in, const int* in_sizes, int n_in,
                              void* d_out, int out_size, void* d_ws, size_t ws_size,
                              hipStream_t stream) {
    const float* gnn_x     = (const float*)d_in[0];
    const float* vanilla_x = (const float*)d_in[1];
    const int*   edge_src  = (const int*)d_in[2];
    const int*   edge_dst  = (const int*)d_in[3];
    const int*   a1_idx    = (const int*)d_in[4];
    const int*   a2_idx    = (const int*)d_in[5];
    const float* Wl1   = (const float*)d_in[6];
    const float* bl1   = (const float*)d_in[7];
    const float* Wr1   = (const float*)d_in[8];
    const float* br1   = (const float*)d_in[9];
    const float* att1  = (const float*)d_in[10];
    const float* bias1 = (const float*)d_in[11];
    const float* Wl2   = (const float*)d_in[12];
    const float* bl2   = (const float*)d_in[13];
    const float* Wr2   = (const float*)d_in[14];
    const float* br2   = (const float*)d_in[15];
    const float* att2  = (const float*)d_in[16];
    const float* bias2 = (const float*)d_in[17];
    const float* Wc    = (const float*)d_in[18];
    const float* bc    = (const float*)d_in[19];
    float* out = (float*)d_out;

    // workspace layout (all sequential-stream safe; x2 aliases xl1/xr1)
    char* p = (char*)d_ws;
    float* xl1 = (float*)p;                       // N*D1
    float* xr1 = xl1 + (size_t)N_NODES * D1;      // N*D1  (xl1+xr1 region == N*D2)
    float* x2  = xl1;                             // aliased: reused after gemm2
    p += (size_t)N_NODES * D2 * sizeof(float);
    float* x1  = (float*)p; p += (size_t)N_NODES * D1 * sizeof(float);
    float* xl2 = (float*)p; p += (size_t)N_NODES * D2 * sizeof(float);
    float* xr2 = (float*)p; p += (size_t)N_NODES * D2 * sizeof(float);
    int* count      = (int*)p; p += (size_t)N_NODES * sizeof(int);
    int* offsets    = (int*)p; p += (size_t)(N_NODES + 1) * sizeof(int);
    int* rank       = (int*)p; p += (size_t)ET * sizeof(int);
    int* sorted_src = (int*)p; p += (size_t)ET * sizeof(int);

    hipMemsetAsync(count, 0, (size_t)N_NODES * sizeof(int), stream);

    int eb = (ET + 255) / 256;
    hist_kernel<<<eb, 256, 0, stream>>>(edge_dst, count, rank);
    scan_kernel<<<1, 1024, 0, stream>>>(count, offsets);
    scatter_kernel<<<eb, 256, 0, stream>>>(edge_src, edge_dst, rank, offsets, sorted_src);

    // layer 1
    dual_gemm_kernel<IN_CH, D1, 16><<<(N_NODES + 15) / 16, 256, 0, stream>>>(
        gnn_x, Wl1, bl1, Wr1, br1, xl1, xr1, N_NODES);
    aggregate1_kernel<<<N_NODES, 128, 0, stream>>>(
        xl1, xr1, att1, bias1, offsets, sorted_src, x1);

    // layer 2
    dual_gemm_kernel<D1, D2, 16><<<(N_NODES + 15) / 16, 512, 0, stream>>>(
        x1, Wl2, bl2, Wr2, br2, xl2, xr2, N_NODES);
    aggregate2_kernel<<<(N_NODES + 3) / 4, 256, 0, stream>>>(
        xl2, xr2, att2, bias2, offsets, sorted_src, x2);

    // classifier
    classifier_kernel<<<BPAIRS, 256, 0, stream>>>(
        vanilla_x, x2, a1_idx, a2_idx, Wc, bc, out);
}

// Round 2
// 425.471 us; speedup vs baseline: 1.1723x; 1.1723x over previous
//
#include <hip/hip_runtime.h>
#include <math.h>

#define N_NODES 20000
#define M_PAD   20032            // 64-row padded for MFMA row tiles
#define E_EDGES 640000
#define ET (E_EDGES + N_NODES)   // edges + self loops
#define IN_CH 256
#define D1 128                   // H1*C1 = 8*16
#define D2 256                   // H2*C2 = 1*256
#define BPAIRS 4096
#define NEG 0.2f

typedef __bf16 bf16x8 __attribute__((ext_vector_type(8)));
typedef float  f32x4  __attribute__((ext_vector_type(4)));

__device__ __forceinline__ unsigned short f2b(float f) {
    unsigned int u = __float_as_uint(f);
    unsigned int r = u + 0x7FFFu + ((u >> 16) & 1u);   // RNE
    return (unsigned short)(r >> 16);
}
__device__ __forceinline__ float b2f(unsigned short h) {
    return __uint_as_float(((unsigned int)h) << 16);
}
__device__ __forceinline__ float lrelu(float s) { return (s > 0.f) ? s : NEG * s; }

// ---------------- CSR build ----------------

__global__ void hist_kernel(const int* __restrict__ edge_dst,
                            int* __restrict__ count, int* __restrict__ rank) {
    int e = blockIdx.x * blockDim.x + threadIdx.x;
    if (e >= ET) return;
    int dst = (e < E_EDGES) ? edge_dst[e] : (e - E_EDGES);
    rank[e] = atomicAdd(&count[dst], 1);
}

__global__ __launch_bounds__(1024) void scan_kernel(const int* __restrict__ count,
                                                    int* __restrict__ offsets) {
    const int PER = (N_NODES + 1023) / 1024;   // 20
    int t = threadIdx.x;
    int base = t * PER;
    int local[PER];
    int sum = 0;
#pragma unroll
    for (int i = 0; i < PER; i++) {
        int idx = base + i;
        int v = (idx < N_NODES) ? count[idx] : 0;
        local[i] = sum;
        sum += v;
    }
    int lane = t & 63, wave = t >> 6;
    int s = sum;
#pragma unroll
    for (int off = 1; off < 64; off <<= 1) {
        int x = __shfl_up(s, off);
        if (lane >= off) s += x;
    }
    __shared__ int wsum[16];
    __shared__ int wpre[16];
    if (lane == 63) wsum[wave] = s;
    __syncthreads();
    if (t == 0) {
        int acc = 0;
        for (int w = 0; w < 16; w++) { wpre[w] = acc; acc += wsum[w]; }
        offsets[N_NODES] = acc;  // == ET
    }
    __syncthreads();
    int thread_excl = wpre[wave] + (s - sum);
#pragma unroll
    for (int i = 0; i < PER; i++) {
        int idx = base + i;
        if (idx < N_NODES) offsets[idx] = thread_excl + local[i];
    }
}

__global__ void scatter_kernel(const int* __restrict__ edge_src,
                               const int* __restrict__ edge_dst,
                               const int* __restrict__ rank,
                               const int* __restrict__ offsets,
                               int* __restrict__ sorted_src) {
    int e = blockIdx.x * blockDim.x + threadIdx.x;
    if (e >= ET) return;
    int dst = (e < E_EDGES) ? edge_dst[e] : (e - E_EDGES);
    int src = (e < E_EDGES) ? edge_src[e] : (e - E_EDGES);
    sorted_src[offsets[dst] + rank[e]] = src;
}

// ---------------- conversions ----------------

// x f32 [M x K] -> bf16 [M_PAD x K], zero pad rows. 4 elems/thread.
template <int K>
__global__ void convert_x_kernel(const float* __restrict__ x,
                                 unsigned short* __restrict__ xb, int M) {
    int idx = blockIdx.x * blockDim.x + threadIdx.x;
    int e0 = idx * 4;
    if (e0 >= M_PAD * K) return;
    int row = e0 / K;
    ushort4 o;
    if (row < M) {
        float4 v = *(const float4*)(x + e0);
        o.x = f2b(v.x); o.y = f2b(v.y); o.z = f2b(v.z); o.w = f2b(v.w);
    } else {
        o.x = o.y = o.z = o.w = 0;
    }
    *(ushort4*)(xb + e0) = o;
}

// W f32 [K x N] -> Wt bf16 [N x K]
template <int K, int N>
__global__ void convert_wt_kernel(const float* __restrict__ W,
                                  unsigned short* __restrict__ Wt) {
    int idx = blockIdx.x * blockDim.x + threadIdx.x;
    if (idx >= K * N) return;
    int k = idx / N, n = idx - k * N;
    Wt[n * K + k] = f2b(W[idx]);
}

// ---------------- MFMA GEMM: Y(bf16, MxN) = A(bf16, M_PADxK) @ Wt^T + bias ----
// block = 256 thr (4 waves). Wave w computes 64 rows x 16 cols (4 MFMA subtiles).
// grid = (M_PAD/64, N/64).
// Fragment layouts (gfx950 16x16x32): a[j]=A[m=lane&15][k=(lane>>4)*8+j],
// b[j]=B[k=(lane>>4)*8+j][n=lane&15], D: col=lane&15, row=(lane>>4)*4+reg.

template <int K>
__global__ __launch_bounds__(256) void gemm_mfma_kernel(
        const unsigned short* __restrict__ A,   // M_PAD x K
        const unsigned short* __restrict__ Wt,  // N x K
        const float* __restrict__ bias,         // N
        unsigned short* __restrict__ Y,         // M x N (bf16)
        int M, int N) {
    int wave = threadIdx.x >> 6;
    int lane = threadIdx.x & 63;
    int row0 = blockIdx.x * 64;
    int col0 = (blockIdx.y * 4 + wave) * 16;
    int rsub = lane & 15;
    int koff = (lane >> 4) * 8;

    const unsigned short* ap = A + (size_t)(row0 + rsub) * K + koff;
    const unsigned short* bp = Wt + (size_t)(col0 + rsub) * K + koff;

    f32x4 acc0 = {0.f, 0.f, 0.f, 0.f};
    f32x4 acc1 = acc0, acc2 = acc0, acc3 = acc0;

#pragma unroll
    for (int kb = 0; kb < K; kb += 32) {
        bf16x8 b  = *(const bf16x8*)(bp + kb);
        bf16x8 a0 = *(const bf16x8*)(ap + kb);
        bf16x8 a1 = *(const bf16x8*)(ap + 16 * K + kb);
        bf16x8 a2 = *(const bf16x8*)(ap + 32 * K + kb);
        bf16x8 a3 = *(const bf16x8*)(ap + 48 * K + kb);
        acc0 = __builtin_amdgcn_mfma_f32_16x16x32_bf16(a0, b, acc0, 0, 0, 0);
        acc1 = __builtin_amdgcn_mfma_f32_16x16x32_bf16(a1, b, acc1, 0, 0, 0);
        acc2 = __builtin_amdgcn_mfma_f32_16x16x32_bf16(a2, b, acc2, 0, 0, 0);
        acc3 = __builtin_amdgcn_mfma_f32_16x16x32_bf16(a3, b, acc3, 0, 0, 0);
    }

    int colg = col0 + rsub;
    float bv = bias[colg];
    int rbase = row0 + (lane >> 4) * 4;
#pragma unroll
    for (int t = 0; t < 4; t++) {
        f32x4 a = (t == 0) ? acc0 : (t == 1) ? acc1 : (t == 2) ? acc2 : acc3;
#pragma unroll
        for (int r = 0; r < 4; r++) {
            int row = rbase + t * 16 + r;
            if (row < M) Y[(size_t)row * N + colg] = f2b(a[r] + bv);
        }
    }
}

// ---------------- layer 1 aggregation: 1 wave per dst, lane -> 2 channels ----

__global__ __launch_bounds__(256) void aggregate1_kernel(
        const unsigned short* __restrict__ xl1, const unsigned short* __restrict__ xr1,
        const float* __restrict__ att1, const float* __restrict__ bias1,
        const int* __restrict__ offsets, const int* __restrict__ sorted_src,
        unsigned short* __restrict__ x1) {
    int wave = threadIdx.x >> 6;
    int lane = threadIdx.x & 63;
    int dst = blockIdx.x * 4 + wave;
    if (dst >= N_NODES) return;
    int c0 = lane * 2;

    ushort2 xru = *(const ushort2*)(xr1 + (size_t)dst * D1 + c0);
    float xr0 = b2f(xru.x), xr1v = b2f(xru.y);
    float a0 = att1[c0], a1 = att1[c0 + 1];
    int beg = offsets[dst], end = offsets[dst + 1];

    float m = -INFINITY, l = 0.f, acc0 = 0.f, acc1 = 0.f;
    for (int i = beg; i < end; i++) {
        int src = sorted_src[i];
        ushort2 vu = *(const ushort2*)(xl1 + (size_t)src * D1 + c0);
        float v0 = b2f(vu.x), v1 = b2f(vu.y);
        float p = a0 * lrelu(v0 + xr0) + a1 * lrelu(v1 + xr1v);
        // reduce over 8 lanes of this head (16 channels)
        p += __shfl_xor(p, 1);
        p += __shfl_xor(p, 2);
        p += __shfl_xor(p, 4);
        float e = p;
        float mnew = fmaxf(m, e);
        float corr = __expf(m - mnew);   // expf(-inf)=0 on first edge
        float pe = __expf(e - mnew);
        l = l * corr + pe;
        acc0 = acc0 * corr + pe * v0;
        acc1 = acc1 * corr + pe * v1;
        m = mnew;
    }
    float inv = 1.f / l;
    ushort2 o;
    o.x = f2b(fmaxf(acc0 * inv + bias1[c0], 0.f));      // + bias, relu
    o.y = f2b(fmaxf(acc1 * inv + bias1[c0 + 1], 0.f));
    *(ushort2*)(x1 + (size_t)dst * D1 + c0) = o;
}

// ---------------- layer 2 aggregation: 1 wave per dst, lane -> 4 channels ----

__global__ __launch_bounds__(256) void aggregate2_kernel(
        const unsigned short* __restrict__ xl2, const unsigned short* __restrict__ xr2,
        const float* __restrict__ att2, const float* __restrict__ bias2,
        const int* __restrict__ offsets, const int* __restrict__ sorted_src,
        float* __restrict__ x2) {
    int wave = threadIdx.x >> 6;
    int lane = threadIdx.x & 63;
    int dst = blockIdx.x * 4 + wave;
    if (dst >= N_NODES) return;
    int c0 = lane * 4;

    ushort4 xru = *(const ushort4*)(xr2 + (size_t)dst * D2 + c0);
    float xr0 = b2f(xru.x), xr1v = b2f(xru.y), xr2v = b2f(xru.z), xr3 = b2f(xru.w);
    float a0 = att2[c0], a1 = att2[c0 + 1], a2 = att2[c0 + 2], a3 = att2[c0 + 3];
    int beg = offsets[dst], end = offsets[dst + 1];

    float m = -INFINITY, l = 0.f;
    float acc0 = 0.f, acc1 = 0.f, acc2 = 0.f, acc3 = 0.f;
    for (int i = beg; i < end; i++) {
        int src = sorted_src[i];
        ushort4 vu = *(const ushort4*)(xl2 + (size_t)src * D2 + c0);
        float v0 = b2f(vu.x), v1 = b2f(vu.y), v2 = b2f(vu.z), v3 = b2f(vu.w);
        float p = a0 * lrelu(v0 + xr0) + a1 * lrelu(v1 + xr1v)
                + a2 * lrelu(v2 + xr2v) + a3 * lrelu(v3 + xr3);
        p += __shfl_xor(p, 1);
        p += __shfl_xor(p, 2);
        p += __shfl_xor(p, 4);
        p += __shfl_xor(p, 8);
        p += __shfl_xor(p, 16);
        p += __shfl_xor(p, 32);
        float e = p;
        float mnew = fmaxf(m, e);
        float corr = __expf(m - mnew);
        float pe = __expf(e - mnew);
        l = l * corr + pe;
        acc0 = acc0 * corr + pe * v0;
        acc1 = acc1 * corr + pe * v1;
        acc2 = acc2 * corr + pe * v2;
        acc3 = acc3 * corr + pe * v3;
        m = mnew;
    }
    float inv = 1.f / l;
    float4 o;
    o.x = acc0 * inv + bias2[c0];
    o.y = acc1 * inv + bias2[c0 + 1];
    o.z = acc2 * inv + bias2[c0 + 2];
    o.w = acc3 * inv + bias2[c0 + 3];
    *(float4*)(x2 + (size_t)dst * D2 + c0) = o;
}

// ---------------- classifier ----------------

__global__ __launch_bounds__(256) void classifier_kernel(
        const float* __restrict__ vanilla_x, const float* __restrict__ x2,
        const int* __restrict__ a1_raw, const int* __restrict__ a2_raw,
        const float* __restrict__ Wc, const float* __restrict__ bc,
        float* __restrict__ out) {
    int b = blockIdx.x;
    int t = threadIdx.x;

    // detect int64 vs int32 storage of index arrays
    __shared__ int stride_s;
    if (t == 0) {
        bool i64 = true;
        for (int i = 1; i < 63; i += 2) i64 = i64 && (a1_raw[i] == 0);
        stride_s = i64 ? 2 : 1;
    }
    __syncthreads();
    int stride = stride_s;
    int a1 = a1_raw[(long)b * stride];
    int a2 = a2_raw[(long)b * stride];

    float s = vanilla_x[a1 * IN_CH + t] * Wc[t]
            + vanilla_x[a2 * IN_CH + t] * Wc[IN_CH + t]
            + x2[a1 * D2 + t] * Wc[2 * IN_CH + t]
            + x2[a2 * D2 + t] * Wc[3 * IN_CH + t];
    s += __shfl_xor(s, 1);
    s += __shfl_xor(s, 2);
    s += __shfl_xor(s, 4);
    s += __shfl_xor(s, 8);
    s += __shfl_xor(s, 16);
    s += __shfl_xor(s, 32);
    __shared__ float part[4];
    if ((t & 63) == 0) part[t >> 6] = s;
    __syncthreads();
    if (t == 0) out[b] = part[0] + part[1] + part[2] + part[3] + bc[0];
}

// ---------------- launch ----------------

extern "C" void kernel_launch(void* const* d_in, const int* in_sizes, int n_in,
                              void* d_out, int out_size, void* d_ws, size_t ws_size,
                              hipStream_t stream) {
    const float* gnn_x     = (const float*)d_in[0];
    const float* vanilla_x = (const float*)d_in[1];
    const int*   edge_src  = (const int*)d_in[2];
    const int*   edge_dst  = (const int*)d_in[3];
    const int*   a1_idx    = (const int*)d_in[4];
    const int*   a2_idx    = (const int*)d_in[5];
    const float* Wl1   = (const float*)d_in[6];
    const float* bl1   = (const float*)d_in[7];
    const float* Wr1   = (const float*)d_in[8];
    const float* br1   = (const float*)d_in[9];
    const float* att1  = (const float*)d_in[10];
    const float* bias1 = (const float*)d_in[11];
    const float* Wl2   = (const float*)d_in[12];
    const float* bl2   = (const float*)d_in[13];
    const float* Wr2   = (const float*)d_in[14];
    const float* br2   = (const float*)d_in[15];
    const float* att2  = (const float*)d_in[16];
    const float* bias2 = (const float*)d_in[17];
    const float* Wc    = (const float*)d_in[18];
    const float* bc    = (const float*)d_in[19];
    float* out = (float*)d_out;

    // workspace layout
    char* p = (char*)d_ws;
    unsigned short* xb   = (unsigned short*)p; p += (size_t)M_PAD * IN_CH * 2;   // 10.26 MB
    unsigned short* x1b  = (unsigned short*)p; p += (size_t)M_PAD * D1 * 2;      // 5.13 MB
    unsigned short* xl1b = (unsigned short*)p; p += (size_t)N_NODES * D1 * 2;
    unsigned short* xr1b = (unsigned short*)p; p += (size_t)N_NODES * D1 * 2;
    unsigned short* xl2b = (unsigned short*)p; p += (size_t)N_NODES * D2 * 2;
    unsigned short* xr2b = (unsigned short*)p; p += (size_t)N_NODES * D2 * 2;
    unsigned short* wt1l = (unsigned short*)p; p += (size_t)D1 * IN_CH * 2;
    unsigned short* wt1r = (unsigned short*)p; p += (size_t)D1 * IN_CH * 2;
    unsigned short* wt2l = (unsigned short*)p; p += (size_t)D2 * D1 * 2;
    unsigned short* wt2r = (unsigned short*)p; p += (size_t)D2 * D1 * 2;
    float* x2 = (float*)p; p += (size_t)N_NODES * D2 * 4;                        // 20.48 MB
    int* count      = (int*)p; p += (size_t)N_NODES * 4;
    int* offsets    = (int*)p; p += (size_t)(N_NODES + 4) * 4;
    int* rank       = (int*)p; p += (size_t)ET * 4;
    int* sorted_src = (int*)p; p += (size_t)ET * 4;

    hipMemsetAsync(count, 0, (size_t)N_NODES * sizeof(int), stream);
    // zero pad rows of x1b (rows N_NODES..M_PAD)
    hipMemsetAsync(x1b + (size_t)N_NODES * D1, 0,
                   (size_t)(M_PAD - N_NODES) * D1 * 2, stream);

    int eb = (ET + 255) / 256;
    hist_kernel<<<eb, 256, 0, stream>>>(edge_dst, count, rank);
    scan_kernel<<<1, 1024, 0, stream>>>(count, offsets);
    scatter_kernel<<<eb, 256, 0, stream>>>(edge_src, edge_dst, rank, offsets, sorted_src);

    // conversions
    convert_x_kernel<IN_CH><<<(M_PAD * IN_CH / 4 + 255) / 256, 256, 0, stream>>>(
        gnn_x, xb, N_NODES);
    convert_wt_kernel<IN_CH, D1><<<(IN_CH * D1 + 255) / 256, 256, 0, stream>>>(Wl1, wt1l);
    convert_wt_kernel<IN_CH, D1><<<(IN_CH * D1 + 255) / 256, 256, 0, stream>>>(Wr1, wt1r);
    convert_wt_kernel<D1, D2><<<(D1 * D2 + 255) / 256, 256, 0, stream>>>(Wl2, wt2l);
    convert_wt_kernel<D1, D2><<<(D1 * D2 + 255) / 256, 256, 0, stream>>>(Wr2, wt2r);

    // layer 1: two MFMA GEMMs + aggregation
    dim3 g1(M_PAD / 64, D1 / 64);   // (313, 2)
    gemm_mfma_kernel<IN_CH><<<g1, 256, 0, stream>>>(xb, wt1l, bl1, xl1b, N_NODES, D1);
    gemm_mfma_kernel<IN_CH><<<g1, 256, 0, stream>>>(xb, wt1r, br1, xr1b, N_NODES, D1);
    aggregate1_kernel<<<(N_NODES + 3) / 4, 256, 0, stream>>>(
        xl1b, xr1b, att1, bias1, offsets, sorted_src, x1b);

    // layer 2
    dim3 g2(M_PAD / 64, D2 / 64);   // (313, 4)
    gemm_mfma_kernel<D1><<<g2, 256, 0, stream>>>(x1b, wt2l, bl2, xl2b, N_NODES, D2);
    gemm_mfma_kernel<D1><<<g2, 256, 0, stream>>>(x1b, wt2r, br2, xr2b, N_NODES, D2);
    aggregate2_kernel<<<(N_NODES + 3) / 4, 256, 0, stream>>>(
        xl2b, xr2b, att2, bias2, offsets, sorted_src, x2);

    // classifier
    classifier_kernel<<<BPAIRS, 256, 0, stream>>>(
        vanilla_x, x2, a1_idx, a2_idx, Wc, bc, out);
}

// Round 3
// 311.339 us; speedup vs baseline: 1.6021x; 1.3666x over previous
//
#include <hip/hip_runtime.h>
#include <math.h>

#define N_NODES 20000
#define M_PAD   20032            // 64-row padded for MFMA row tiles
#define E_EDGES 640000
#define ET (E_EDGES + N_NODES)   // edges + self loops
#define IN_CH 256
#define D1 128                   // H1*C1 = 8*16
#define D2 256                   // H2*C2 = 1*256
#define BPAIRS 4096
#define NEG 0.2f

#define XCONV_BLOCKS 5008        // M_PAD*IN_CH/4/256
#define WCONV_BLOCKS 512         // 131072/256

typedef __bf16 bf16x8 __attribute__((ext_vector_type(8)));
typedef float  f32x4  __attribute__((ext_vector_type(4)));

__device__ __forceinline__ unsigned short f2b(float f) {
    unsigned int u = __float_as_uint(f);
    unsigned int r = u + 0x7FFFu + ((u >> 16) & 1u);   // RNE
    return (unsigned short)(r >> 16);
}
__device__ __forceinline__ float b2f(unsigned short h) {
    return __uint_as_float(((unsigned int)h) << 16);
}
__device__ __forceinline__ float lrelu(float s) { return (s > 0.f) ? s : NEG * s; }

// ---------------- CSR build ----------------

__global__ void hist_kernel(const int* __restrict__ edge_dst,
                            int* __restrict__ count, int* __restrict__ rank) {
    int e = blockIdx.x * blockDim.x + threadIdx.x;
    if (e >= ET) return;
    int dst = (e < E_EDGES) ? edge_dst[e] : (e - E_EDGES);
    rank[e] = atomicAdd(&count[dst], 1);
}

__global__ __launch_bounds__(1024) void scan_kernel(const int* __restrict__ count,
                                                    int* __restrict__ offsets) {
    const int PER = 20;          // 20480 slots >= N_NODES
    int t = threadIdx.x;
    int base = t * PER;
    int local[PER];
    int sum = 0;
    int vals[PER];
    const int4* c4 = (const int4*)(count);
#pragma unroll
    for (int q = 0; q < 5; q++) {
        int idx4 = (base >> 2) + q;
        int4 v = (base + q * 4 + 3 < N_NODES) ? c4[idx4] : make_int4(
            (base + q * 4 + 0 < N_NODES) ? count[base + q * 4 + 0] : 0,
            (base + q * 4 + 1 < N_NODES) ? count[base + q * 4 + 1] : 0,
            (base + q * 4 + 2 < N_NODES) ? count[base + q * 4 + 2] : 0,
            (base + q * 4 + 3 < N_NODES) ? count[base + q * 4 + 3] : 0);
        vals[q * 4 + 0] = v.x; vals[q * 4 + 1] = v.y;
        vals[q * 4 + 2] = v.z; vals[q * 4 + 3] = v.w;
    }
#pragma unroll
    for (int i = 0; i < PER; i++) {
        local[i] = sum;
        sum += vals[i];
    }
    int lane = t & 63, wave = t >> 6;
    int s = sum;
#pragma unroll
    for (int off = 1; off < 64; off <<= 1) {
        int x = __shfl_up(s, off);
        if (lane >= off) s += x;
    }
    __shared__ int wsum[16];
    __shared__ int wpre[16];
    if (lane == 63) wsum[wave] = s;
    __syncthreads();
    if (t == 0) {
        int acc = 0;
        for (int w = 0; w < 16; w++) { wpre[w] = acc; acc += wsum[w]; }
        offsets[N_NODES] = acc;  // == ET
    }
    __syncthreads();
    int thread_excl = wpre[wave] + (s - sum);
#pragma unroll
    for (int i = 0; i < PER; i++) {
        int idx = base + i;
        if (idx < N_NODES) offsets[idx] = thread_excl + local[i];
    }
}

__global__ void scatter_kernel(const int* __restrict__ edge_src,
                               const int* __restrict__ edge_dst,
                               const int* __restrict__ rank,
                               const int* __restrict__ offsets,
                               int* __restrict__ sorted_src) {
    int e = blockIdx.x * blockDim.x + threadIdx.x;
    if (e >= ET) return;
    int dst = (e < E_EDGES) ? edge_dst[e] : (e - E_EDGES);
    int src = (e < E_EDGES) ? edge_src[e] : (e - E_EDGES);
    sorted_src[offsets[dst] + rank[e]] = src;
}

// ---------------- fused conversions: x -> bf16 padded, 4 weights -> bf16^T ----

__global__ void convert_all_kernel(
        const float* __restrict__ gnn_x,
        const float* __restrict__ Wl1, const float* __restrict__ Wr1,
        const float* __restrict__ Wl2, const float* __restrict__ Wr2,
        unsigned short* __restrict__ xb,
        unsigned short* __restrict__ wt1l, unsigned short* __restrict__ wt1r,
        unsigned short* __restrict__ wt2l, unsigned short* __restrict__ wt2r) {
    int bid = blockIdx.x;
    if (bid < XCONV_BLOCKS) {
        int e0 = (bid * 256 + threadIdx.x) * 4;
        int row = e0 >> 8;                 // / IN_CH
        ushort4 o;
        if (row < N_NODES) {
            float4 v = *(const float4*)(gnn_x + e0);
            o.x = f2b(v.x); o.y = f2b(v.y); o.z = f2b(v.z); o.w = f2b(v.w);
        } else {
            o.x = o.y = o.z = o.w = 0;
        }
        *(ushort4*)(xb + e0) = o;
    } else {
        int idx = (bid - XCONV_BLOCKS) * 256 + threadIdx.x;  // 0..131071
        int seg = idx >> 15;               // 4 segments of 32768
        int r = idx & 32767;
        const float* W;
        unsigned short* Wt;
        int k, n, K;
        if (seg < 2) {                     // layer1: K=256, N=128
            W = seg ? Wr1 : Wl1; Wt = seg ? wt1r : wt1l;
            k = r >> 7; n = r & 127; K = IN_CH;
        } else {                           // layer2: K=128, N=256
            W = (seg & 1) ? Wr2 : Wl2; Wt = (seg & 1) ? wt2r : wt2l;
            k = r >> 8; n = r & 255; K = D1;
        }
        Wt[n * K + k] = f2b(W[r]);
    }
}

// ---------------- dual MFMA GEMM: Yl = A@Wl^T+bl, Yr = A@Wr^T+br -------------
// block = 256 thr (4 waves). Wave computes 64 rows x 16 cols for BOTH outputs,
// reusing the 4 A fragments (8 MFMA per 6 x 16B loads).
// grid = (M_PAD/64, NOUT/64). Fragments (gfx950 16x16x32):
// a[j]=A[m=lane&15][k=(lane>>4)*8+j], b[j]=B[k=(lane>>4)*8+j][n=lane&15],
// D: col=lane&15, row=(lane>>4)*4+reg.

template <int K>
__global__ __launch_bounds__(256) void dual_gemm_mfma_kernel(
        const unsigned short* __restrict__ A,    // M_PAD x K
        const unsigned short* __restrict__ Wtl,  // NOUT x K
        const unsigned short* __restrict__ Wtr,  // NOUT x K
        const float* __restrict__ bl, const float* __restrict__ br,
        unsigned short* __restrict__ Yl, unsigned short* __restrict__ Yr,
        int M, int NOUT) {
    int wave = threadIdx.x >> 6;
    int lane = threadIdx.x & 63;
    int row0 = blockIdx.x * 64;
    int col0 = (blockIdx.y * 4 + wave) * 16;
    int rsub = lane & 15;
    int koff = (lane >> 4) * 8;

    const unsigned short* ap  = A   + (size_t)(row0 + rsub) * K + koff;
    const unsigned short* bpl = Wtl + (size_t)(col0 + rsub) * K + koff;
    const unsigned short* bpr = Wtr + (size_t)(col0 + rsub) * K + koff;

    f32x4 l0 = {0.f, 0.f, 0.f, 0.f};
    f32x4 l1 = l0, l2 = l0, l3 = l0, r0 = l0, r1 = l0, r2 = l0, r3 = l0;

#pragma unroll
    for (int kb = 0; kb < K; kb += 32) {
        bf16x8 bfl = *(const bf16x8*)(bpl + kb);
        bf16x8 bfr = *(const bf16x8*)(bpr + kb);
        bf16x8 a0 = *(const bf16x8*)(ap + kb);
        bf16x8 a1 = *(const bf16x8*)(ap + 16 * K + kb);
        bf16x8 a2 = *(const bf16x8*)(ap + 32 * K + kb);
        bf16x8 a3 = *(const bf16x8*)(ap + 48 * K + kb);
        l0 = __builtin_amdgcn_mfma_f32_16x16x32_bf16(a0, bfl, l0, 0, 0, 0);
        r0 = __builtin_amdgcn_mfma_f32_16x16x32_bf16(a0, bfr, r0, 0, 0, 0);
        l1 = __builtin_amdgcn_mfma_f32_16x16x32_bf16(a1, bfl, l1, 0, 0, 0);
        r1 = __builtin_amdgcn_mfma_f32_16x16x32_bf16(a1, bfr, r1, 0, 0, 0);
        l2 = __builtin_amdgcn_mfma_f32_16x16x32_bf16(a2, bfl, l2, 0, 0, 0);
        r2 = __builtin_amdgcn_mfma_f32_16x16x32_bf16(a2, bfr, r2, 0, 0, 0);
        l3 = __builtin_amdgcn_mfma_f32_16x16x32_bf16(a3, bfl, l3, 0, 0, 0);
        r3 = __builtin_amdgcn_mfma_f32_16x16x32_bf16(a3, bfr, r3, 0, 0, 0);
    }

    int colg = col0 + rsub;
    float bvl = bl[colg];
    float bvr = br[colg];
    int rbase = row0 + (lane >> 4) * 4;
#pragma unroll
    for (int t = 0; t < 4; t++) {
        f32x4 al = (t == 0) ? l0 : (t == 1) ? l1 : (t == 2) ? l2 : l3;
        f32x4 ar = (t == 0) ? r0 : (t == 1) ? r1 : (t == 2) ? r2 : r3;
#pragma unroll
        for (int r = 0; r < 4; r++) {
            int row = rbase + t * 16 + r;
            if (row < M) {
                Yl[(size_t)row * NOUT + colg] = f2b(al[r] + bvl);
                Yr[(size_t)row * NOUT + colg] = f2b(ar[r] + bvr);
            }
        }
    }
}

// ---------------- layer 1 aggregation: 1 wave/dst, lane -> 2 ch, ILP-4 ------

__global__ __launch_bounds__(256) void aggregate1_kernel(
        const unsigned short* __restrict__ xl1, const unsigned short* __restrict__ xr1,
        const float* __restrict__ att1, const float* __restrict__ bias1,
        const int* __restrict__ offsets, const int* __restrict__ sorted_src,
        unsigned short* __restrict__ x1) {
    int wave = threadIdx.x >> 6;
    int lane = threadIdx.x & 63;
    int dst = blockIdx.x * 4 + wave;
    if (dst >= M_PAD) return;
    int c0 = lane * 2;
    if (dst >= N_NODES) {                  // zero pad rows for the next GEMM
        ushort2 z; z.x = 0; z.y = 0;
        *(ushort2*)(x1 + (size_t)dst * D1 + c0) = z;
        return;
    }

    ushort2 xru = *(const ushort2*)(xr1 + (size_t)dst * D1 + c0);
    float xr0 = b2f(xru.x), xr1v = b2f(xru.y);
    float a0 = att1[c0], a1 = att1[c0 + 1];
    int beg = offsets[dst], end = offsets[dst + 1];

    float m = -INFINITY, l = 0.f, A0 = 0.f, A1 = 0.f;
    int i = beg;
    for (; i + 4 <= end; i += 4) {
        int s0 = sorted_src[i], s1 = sorted_src[i + 1];
        int s2 = sorted_src[i + 2], s3 = sorted_src[i + 3];
        ushort2 u0 = *(const ushort2*)(xl1 + (size_t)s0 * D1 + c0);
        ushort2 u1 = *(const ushort2*)(xl1 + (size_t)s1 * D1 + c0);
        ushort2 u2 = *(const ushort2*)(xl1 + (size_t)s2 * D1 + c0);
        ushort2 u3 = *(const ushort2*)(xl1 + (size_t)s3 * D1 + c0);
        float v00 = b2f(u0.x), v01 = b2f(u0.y);
        float v10 = b2f(u1.x), v11 = b2f(u1.y);
        float v20 = b2f(u2.x), v21 = b2f(u2.y);
        float v30 = b2f(u3.x), v31 = b2f(u3.y);
        float p0 = a0 * lrelu(v00 + xr0) + a1 * lrelu(v01 + xr1v);
        float p1 = a0 * lrelu(v10 + xr0) + a1 * lrelu(v11 + xr1v);
        float p2 = a0 * lrelu(v20 + xr0) + a1 * lrelu(v21 + xr1v);
        float p3 = a0 * lrelu(v30 + xr0) + a1 * lrelu(v31 + xr1v);
        // reduce over 8 lanes of each head (independent trees)
        p0 += __shfl_xor(p0, 1); p1 += __shfl_xor(p1, 1);
        p2 += __shfl_xor(p2, 1); p3 += __shfl_xor(p3, 1);
        p0 += __shfl_xor(p0, 2); p1 += __shfl_xor(p1, 2);
        p2 += __shfl_xor(p2, 2); p3 += __shfl_xor(p3, 2);
        p0 += __shfl_xor(p0, 4); p1 += __shfl_xor(p1, 4);
        p2 += __shfl_xor(p2, 4); p3 += __shfl_xor(p3, 4);
        float mn = fmaxf(fmaxf(fmaxf(p0, p1), fmaxf(p2, p3)), m);
        float corr = __expf(m - mn);
        float e0 = __expf(p0 - mn), e1 = __expf(p1 - mn);
        float e2 = __expf(p2 - mn), e3 = __expf(p3 - mn);
        l = l * corr + (e0 + e1) + (e2 + e3);
        A0 = A0 * corr + e0 * v00 + e1 * v10 + e2 * v20 + e3 * v30;
        A1 = A1 * corr + e0 * v01 + e1 * v11 + e2 * v21 + e3 * v31;
        m = mn;
    }
    for (; i < end; i++) {
        int src = sorted_src[i];
        ushort2 vu = *(const ushort2*)(xl1 + (size_t)src * D1 + c0);
        float v0 = b2f(vu.x), v1 = b2f(vu.y);
        float p = a0 * lrelu(v0 + xr0) + a1 * lrelu(v1 + xr1v);
        p += __shfl_xor(p, 1);
        p += __shfl_xor(p, 2);
        p += __shfl_xor(p, 4);
        float mn = fmaxf(m, p);
        float corr = __expf(m - mn);
        float pe = __expf(p - mn);
        l = l * corr + pe;
        A0 = A0 * corr + pe * v0;
        A1 = A1 * corr + pe * v1;
        m = mn;
    }
    float inv = 1.f / l;
    ushort2 o;
    o.x = f2b(fmaxf(A0 * inv + bias1[c0], 0.f));       // + bias, relu
    o.y = f2b(fmaxf(A1 * inv + bias1[c0 + 1], 0.f));
    *(ushort2*)(x1 + (size_t)dst * D1 + c0) = o;
}

// ---------------- layer 2 aggregation: 1 wave/dst, lane -> 4 ch, ILP-4 ------

__global__ __launch_bounds__(256) void aggregate2_kernel(
        const unsigned short* __restrict__ xl2, const unsigned short* __restrict__ xr2,
        const float* __restrict__ att2, const float* __restrict__ bias2,
        const int* __restrict__ offsets, const int* __restrict__ sorted_src,
        float* __restrict__ x2) {
    int wave = threadIdx.x >> 6;
    int lane = threadIdx.x & 63;
    int dst = blockIdx.x * 4 + wave;
    if (dst >= N_NODES) return;
    int c0 = lane * 4;

    ushort4 xru = *(const ushort4*)(xr2 + (size_t)dst * D2 + c0);
    float xr0 = b2f(xru.x), xr1v = b2f(xru.y), xr2v = b2f(xru.z), xr3 = b2f(xru.w);
    float a0 = att2[c0], a1 = att2[c0 + 1], a2 = att2[c0 + 2], a3 = att2[c0 + 3];
    int beg = offsets[dst], end = offsets[dst + 1];

    float m = -INFINITY, l = 0.f;
    float A0 = 0.f, A1 = 0.f, A2 = 0.f, A3 = 0.f;
    int i = beg;
    for (; i + 4 <= end; i += 4) {
        int s0 = sorted_src[i], s1 = sorted_src[i + 1];
        int s2 = sorted_src[i + 2], s3 = sorted_src[i + 3];
        ushort4 u0 = *(const ushort4*)(xl2 + (size_t)s0 * D2 + c0);
        ushort4 u1 = *(const ushort4*)(xl2 + (size_t)s1 * D2 + c0);
        ushort4 u2 = *(const ushort4*)(xl2 + (size_t)s2 * D2 + c0);
        ushort4 u3 = *(const ushort4*)(xl2 + (size_t)s3 * D2 + c0);
        float v00 = b2f(u0.x), v01 = b2f(u0.y), v02 = b2f(u0.z), v03 = b2f(u0.w);
        float v10 = b2f(u1.x), v11 = b2f(u1.y), v12 = b2f(u1.z), v13 = b2f(u1.w);
        float v20 = b2f(u2.x), v21 = b2f(u2.y), v22 = b2f(u2.z), v23 = b2f(u2.w);
        float v30 = b2f(u3.x), v31 = b2f(u3.y), v32 = b2f(u3.z), v33 = b2f(u3.w);
        float p0 = a0 * lrelu(v00 + xr0) + a1 * lrelu(v01 + xr1v)
                 + a2 * lrelu(v02 + xr2v) + a3 * lrelu(v03 + xr3);
        float p1 = a0 * lrelu(v10 + xr0) + a1 * lrelu(v11 + xr1v)
                 + a2 * lrelu(v12 + xr2v) + a3 * lrelu(v13 + xr3);
        float p2 = a0 * lrelu(v20 + xr0) + a1 * lrelu(v21 + xr1v)
                 + a2 * lrelu(v22 + xr2v) + a3 * lrelu(v23 + xr3);
        float p3 = a0 * lrelu(v30 + xr0) + a1 * lrelu(v31 + xr1v)
                 + a2 * lrelu(v32 + xr2v) + a3 * lrelu(v33 + xr3);
        p0 += __shfl_xor(p0, 1);  p1 += __shfl_xor(p1, 1);
        p2 += __shfl_xor(p2, 1);  p3 += __shfl_xor(p3, 1);
        p0 += __shfl_xor(p0, 2);  p1 += __shfl_xor(p1, 2);
        p2 += __shfl_xor(p2, 2);  p3 += __shfl_xor(p3, 2);
        p0 += __shfl_xor(p0, 4);  p1 += __shfl_xor(p1, 4);
        p2 += __shfl_xor(p2, 4);  p3 += __shfl_xor(p3, 4);
        p0 += __shfl_xor(p0, 8);  p1 += __shfl_xor(p1, 8);
        p2 += __shfl_xor(p2, 8);  p3 += __shfl_xor(p3, 8);
        p0 += __shfl_xor(p0, 16); p1 += __shfl_xor(p1, 16);
        p2 += __shfl_xor(p2, 16); p3 += __shfl_xor(p3, 16);
        p0 += __shfl_xor(p0, 32); p1 += __shfl_xor(p1, 32);
        p2 += __shfl_xor(p2, 32); p3 += __shfl_xor(p3, 32);
        float mn = fmaxf(fmaxf(fmaxf(p0, p1), fmaxf(p2, p3)), m);
        float corr = __expf(m - mn);
        float e0 = __expf(p0 - mn), e1 = __expf(p1 - mn);
        float e2 = __expf(p2 - mn), e3 = __expf(p3 - mn);
        l = l * corr + (e0 + e1) + (e2 + e3);
        A0 = A0 * corr + e0 * v00 + e1 * v10 + e2 * v20 + e3 * v30;
        A1 = A1 * corr + e0 * v01 + e1 * v11 + e2 * v21 + e3 * v31;
        A2 = A2 * corr + e0 * v02 + e1 * v12 + e2 * v22 + e3 * v32;
        A3 = A3 * corr + e0 * v03 + e1 * v13 + e2 * v23 + e3 * v33;
        m = mn;
    }
    for (; i < end; i++) {
        int src = sorted_src[i];
        ushort4 vu = *(const ushort4*)(xl2 + (size_t)src * D2 + c0);
        float v0 = b2f(vu.x), v1 = b2f(vu.y), v2 = b2f(vu.z), v3 = b2f(vu.w);
        float p = a0 * lrelu(v0 + xr0) + a1 * lrelu(v1 + xr1v)
                + a2 * lrelu(v2 + xr2v) + a3 * lrelu(v3 + xr3);
        p += __shfl_xor(p, 1);
        p += __shfl_xor(p, 2);
        p += __shfl_xor(p, 4);
        p += __shfl_xor(p, 8);
        p += __shfl_xor(p, 16);
        p += __shfl_xor(p, 32);
        float mn = fmaxf(m, p);
        float corr = __expf(m - mn);
        float pe = __expf(p - mn);
        l = l * corr + pe;
        A0 = A0 * corr + pe * v0;
        A1 = A1 * corr + pe * v1;
        A2 = A2 * corr + pe * v2;
        A3 = A3 * corr + pe * v3;
        m = mn;
    }
    float inv = 1.f / l;
    float4 o;
    o.x = A0 * inv + bias2[c0];
    o.y = A1 * inv + bias2[c0 + 1];
    o.z = A2 * inv + bias2[c0 + 2];
    o.w = A3 * inv + bias2[c0 + 3];
    *(float4*)(x2 + (size_t)dst * D2 + c0) = o;
}

// ---------------- classifier ----------------

__global__ __launch_bounds__(256) void classifier_kernel(
        const float* __restrict__ vanilla_x, const float* __restrict__ x2,
        const int* __restrict__ a1_raw, const int* __restrict__ a2_raw,
        const float* __restrict__ Wc, const float* __restrict__ bc,
        float* __restrict__ out) {
    int b = blockIdx.x;
    int t = threadIdx.x;

    // detect int64 vs int32 storage of index arrays
    __shared__ int stride_s;
    if (t == 0) {
        bool i64 = true;
        for (int i = 1; i < 63; i += 2) i64 = i64 && (a1_raw[i] == 0);
        stride_s = i64 ? 2 : 1;
    }
    __syncthreads();
    int stride = stride_s;
    int a1 = a1_raw[(long)b * stride];
    int a2 = a2_raw[(long)b * stride];

    float s = vanilla_x[a1 * IN_CH + t] * Wc[t]
            + vanilla_x[a2 * IN_CH + t] * Wc[IN_CH + t]
            + x2[a1 * D2 + t] * Wc[2 * IN_CH + t]
            + x2[a2 * D2 + t] * Wc[3 * IN_CH + t];
    s += __shfl_xor(s, 1);
    s += __shfl_xor(s, 2);
    s += __shfl_xor(s, 4);
    s += __shfl_xor(s, 8);
    s += __shfl_xor(s, 16);
    s += __shfl_xor(s, 32);
    __shared__ float part[4];
    if ((t & 63) == 0) part[t >> 6] = s;
    __syncthreads();
    if (t == 0) out[b] = part[0] + part[1] + part[2] + part[3] + bc[0];
}

// ---------------- launch ----------------

extern "C" void kernel_launch(void* const* d_in, const int* in_sizes, int n_in,
                              void* d_out, int out_size, void* d_ws, size_t ws_size,
                              hipStream_t stream) {
    const float* gnn_x     = (const float*)d_in[0];
    const float* vanilla_x = (const float*)d_in[1];
    const int*   edge_src  = (const int*)d_in[2];
    const int*   edge_dst  = (const int*)d_in[3];
    const int*   a1_idx    = (const int*)d_in[4];
    const int*   a2_idx    = (const int*)d_in[5];
    const float* Wl1   = (const float*)d_in[6];
    const float* bl1   = (const float*)d_in[7];
    const float* Wr1   = (const float*)d_in[8];
    const float* br1   = (const float*)d_in[9];
    const float* att1  = (const float*)d_in[10];
    const float* bias1 = (const float*)d_in[11];
    const float* Wl2   = (const float*)d_in[12];
    const float* bl2   = (const float*)d_in[13];
    const float* Wr2   = (const float*)d_in[14];
    const float* br2   = (const float*)d_in[15];
    const float* att2  = (const float*)d_in[16];
    const float* bias2 = (const float*)d_in[17];
    const float* Wc    = (const float*)d_in[18];
    const float* bc    = (const float*)d_in[19];
    float* out = (float*)d_out;

    // workspace layout
    char* p = (char*)d_ws;
    unsigned short* xb   = (unsigned short*)p; p += (size_t)M_PAD * IN_CH * 2;
    unsigned short* x1b  = (unsigned short*)p; p += (size_t)M_PAD * D1 * 2;
    unsigned short* xl1b = (unsigned short*)p; p += (size_t)N_NODES * D1 * 2;
    unsigned short* xr1b = (unsigned short*)p; p += (size_t)N_NODES * D1 * 2;
    unsigned short* xl2b = (unsigned short*)p; p += (size_t)N_NODES * D2 * 2;
    unsigned short* xr2b = (unsigned short*)p; p += (size_t)N_NODES * D2 * 2;
    unsigned short* wt1l = (unsigned short*)p; p += (size_t)D1 * IN_CH * 2;
    unsigned short* wt1r = (unsigned short*)p; p += (size_t)D1 * IN_CH * 2;
    unsigned short* wt2l = (unsigned short*)p; p += (size_t)D2 * D1 * 2;
    unsigned short* wt2r = (unsigned short*)p; p += (size_t)D2 * D1 * 2;
    float* x2 = (float*)p; p += (size_t)N_NODES * D2 * 4;
    int* count      = (int*)p; p += (size_t)N_NODES * 4;
    int* offsets    = (int*)p; p += (size_t)(N_NODES + 4) * 4;
    int* rank       = (int*)p; p += (size_t)ET * 4;
    int* sorted_src = (int*)p; p += (size_t)ET * 4;

    hipMemsetAsync(count, 0, (size_t)N_NODES * sizeof(int), stream);

    int eb = (ET + 255) / 256;
    hist_kernel<<<eb, 256, 0, stream>>>(edge_dst, count, rank);
    scan_kernel<<<1, 1024, 0, stream>>>(count, offsets);
    scatter_kernel<<<eb, 256, 0, stream>>>(edge_src, edge_dst, rank, offsets, sorted_src);

    convert_all_kernel<<<XCONV_BLOCKS + WCONV_BLOCKS, 256, 0, stream>>>(
        gnn_x, Wl1, Wr1, Wl2, Wr2, xb, wt1l, wt1r, wt2l, wt2r);

    // layer 1: fused dual GEMM + aggregation
    dim3 g1(M_PAD / 64, D1 / 64);   // (313, 2)
    dual_gemm_mfma_kernel<IN_CH><<<g1, 256, 0, stream>>>(
        xb, wt1l, wt1r, bl1, br1, xl1b, xr1b, N_NODES, D1);
    aggregate1_kernel<<<M_PAD / 4, 256, 0, stream>>>(
        xl1b, xr1b, att1, bias1, offsets, sorted_src, x1b);

    // layer 2
    dim3 g2(M_PAD / 64, D2 / 64);   // (313, 4)
    dual_gemm_mfma_kernel<D1><<<g2, 256, 0, stream>>>(
        x1b, wt2l, wt2r, bl2, br2, xl2b, xr2b, N_NODES, D2);
    aggregate2_kernel<<<(N_NODES + 3) / 4, 256, 0, stream>>>(
        xl2b, xr2b, att2, bias2, offsets, sorted_src, x2);

    // classifier
    classifier_kernel<<<BPAIRS, 256, 0, stream>>>(
        vanilla_x, x2, a1_idx, a2_idx, Wc, bc, out);
}

// Round 4
// 298.833 us; speedup vs baseline: 1.6691x; 1.0418x over previous
//
#include <hip/hip_runtime.h>
#include <math.h>

#define N_NODES 20000
#define M_PAD   20032            // 64-row padded for MFMA row tiles
#define E_EDGES 640000
#define ET (E_EDGES + N_NODES)   // edges + self loops
#define IN_CH 256
#define D1 128                   // H1*C1 = 8*16
#define D2 256                   // H2*C2 = 1*256
#define BPAIRS 4096
#define NEG 0.2f
#define LOG2E 1.4426950408889634f

#define XCONV_BLOCKS 5008        // M_PAD*IN_CH/4/256
#define WCONV_BLOCKS 512         // 131072/256
#define HIST_BLOCKS  ((ET + 255) / 256)

#if __has_builtin(__builtin_amdgcn_exp2f)
#define EXP2F(x) __builtin_amdgcn_exp2f(x)
#else
#define EXP2F(x) exp2f(x)
#endif

typedef __bf16 bf16x8 __attribute__((ext_vector_type(8)));
typedef float  f32x4  __attribute__((ext_vector_type(4)));

__device__ __forceinline__ unsigned short f2b(float f) {
    unsigned int u = __float_as_uint(f);
    unsigned int r = u + 0x7FFFu + ((u >> 16) & 1u);   // RNE
    return (unsigned short)(r >> 16);
}
__device__ __forceinline__ float b2f(unsigned short h) {
    return __uint_as_float(((unsigned int)h) << 16);
}
// lrelu(s) = max(s, 0.2*s)  (2 instrs: mul + max)
__device__ __forceinline__ float lrelu(float s) { return fmaxf(s, NEG * s); }

// unpack 8 bf16 (uint4) -> 8 f32
__device__ __forceinline__ void unpack8(uint4 u, float* v) {
    v[0] = __uint_as_float(u.x << 16); v[1] = __uint_as_float(u.x & 0xFFFF0000u);
    v[2] = __uint_as_float(u.y << 16); v[3] = __uint_as_float(u.y & 0xFFFF0000u);
    v[4] = __uint_as_float(u.z << 16); v[5] = __uint_as_float(u.z & 0xFFFF0000u);
    v[6] = __uint_as_float(u.w << 16); v[7] = __uint_as_float(u.w & 0xFFFF0000u);
}
__device__ __forceinline__ void unpack4(uint2 u, float* v) {
    v[0] = __uint_as_float(u.x << 16); v[1] = __uint_as_float(u.x & 0xFFFF0000u);
    v[2] = __uint_as_float(u.y << 16); v[3] = __uint_as_float(u.y & 0xFFFF0000u);
}

// ---------------- fused prep: x->bf16, weights->bf16^T, dst histogram -------

__global__ void prep_kernel(
        const float* __restrict__ gnn_x,
        const float* __restrict__ Wl1, const float* __restrict__ Wr1,
        const float* __restrict__ Wl2, const float* __restrict__ Wr2,
        const int* __restrict__ edge_dst,
        unsigned short* __restrict__ xb,
        unsigned short* __restrict__ wt1l, unsigned short* __restrict__ wt1r,
        unsigned short* __restrict__ wt2l, unsigned short* __restrict__ wt2r,
        int* __restrict__ count, int* __restrict__ rank) {
    int bid = blockIdx.x;
    if (bid < XCONV_BLOCKS) {
        int e0 = (bid * 256 + threadIdx.x) * 4;
        int row = e0 >> 8;                 // / IN_CH
        ushort4 o;
        if (row < N_NODES) {
            float4 v = *(const float4*)(gnn_x + e0);
            o.x = f2b(v.x); o.y = f2b(v.y); o.z = f2b(v.z); o.w = f2b(v.w);
        } else {
            o.x = o.y = o.z = o.w = 0;
        }
        *(ushort4*)(xb + e0) = o;
    } else if (bid < XCONV_BLOCKS + WCONV_BLOCKS) {
        int idx = (bid - XCONV_BLOCKS) * 256 + threadIdx.x;  // 0..131071
        int seg = idx >> 15;               // 4 segments of 32768
        int r = idx & 32767;
        const float* W;
        unsigned short* Wt;
        int k, n, K;
        if (seg < 2) {                     // layer1: K=256, N=128
            W = seg ? Wr1 : Wl1; Wt = seg ? wt1r : wt1l;
            k = r >> 7; n = r & 127; K = IN_CH;
        } else {                           // layer2: K=128, N=256
            W = (seg & 1) ? Wr2 : Wl2; Wt = (seg & 1) ? wt2r : wt2l;
            k = r >> 8; n = r & 255; K = D1;
        }
        Wt[n * K + k] = f2b(W[r]);
    } else {
        int e = (bid - XCONV_BLOCKS - WCONV_BLOCKS) * 256 + threadIdx.x;
        if (e >= ET) return;
        int dst = (e < E_EDGES) ? edge_dst[e] : (e - E_EDGES);
        rank[e] = atomicAdd(&count[dst], 1);
    }
}

// ---------------- CSR scan + scatter ----------------

__global__ __launch_bounds__(1024) void scan_kernel(const int* __restrict__ count,
                                                    int* __restrict__ offsets) {
    const int PER = 20;
    int t = threadIdx.x;
    int base = t * PER;
    int local[PER];
    int sum = 0;
#pragma unroll
    for (int i = 0; i < PER; i++) {
        int idx = base + i;
        int v = (idx < N_NODES) ? count[idx] : 0;
        local[i] = sum;
        sum += v;
    }
    int lane = t & 63, wave = t >> 6;
    int s = sum;
#pragma unroll
    for (int off = 1; off < 64; off <<= 1) {
        int x = __shfl_up(s, off);
        if (lane >= off) s += x;
    }
    __shared__ int wsum[16];
    __shared__ int wpre[16];
    if (lane == 63) wsum[wave] = s;
    __syncthreads();
    if (t == 0) {
        int acc = 0;
        for (int w = 0; w < 16; w++) { wpre[w] = acc; acc += wsum[w]; }
        offsets[N_NODES] = acc;  // == ET
    }
    __syncthreads();
    int thread_excl = wpre[wave] + (s - sum);
#pragma unroll
    for (int i = 0; i < PER; i++) {
        int idx = base + i;
        if (idx < N_NODES) offsets[idx] = thread_excl + local[i];
    }
}

__global__ void scatter_kernel(const int* __restrict__ edge_src,
                               const int* __restrict__ edge_dst,
                               const int* __restrict__ rank,
                               const int* __restrict__ offsets,
                               int* __restrict__ sorted_src) {
    int e = blockIdx.x * blockDim.x + threadIdx.x;
    if (e >= ET) return;
    int dst = (e < E_EDGES) ? edge_dst[e] : (e - E_EDGES);
    int src = (e < E_EDGES) ? edge_src[e] : (e - E_EDGES);
    sorted_src[offsets[dst] + rank[e]] = src;
}

// ---------------- dual MFMA GEMM: Yl = A@Wl^T+bl, Yr = A@Wr^T+br -------------

template <int K>
__global__ __launch_bounds__(256) void dual_gemm_mfma_kernel(
        const unsigned short* __restrict__ A,    // M_PAD x K
        const unsigned short* __restrict__ Wtl,  // NOUT x K
        const unsigned short* __restrict__ Wtr,  // NOUT x K
        const float* __restrict__ bl, const float* __restrict__ br,
        unsigned short* __restrict__ Yl, unsigned short* __restrict__ Yr,
        int M, int NOUT) {
    int wave = threadIdx.x >> 6;
    int lane = threadIdx.x & 63;
    int row0 = blockIdx.x * 64;
    int col0 = (blockIdx.y * 4 + wave) * 16;
    int rsub = lane & 15;
    int koff = (lane >> 4) * 8;

    const unsigned short* ap  = A   + (size_t)(row0 + rsub) * K + koff;
    const unsigned short* bpl = Wtl + (size_t)(col0 + rsub) * K + koff;
    const unsigned short* bpr = Wtr + (size_t)(col0 + rsub) * K + koff;

    f32x4 l0 = {0.f, 0.f, 0.f, 0.f};
    f32x4 l1 = l0, l2 = l0, l3 = l0, r0 = l0, r1 = l0, r2 = l0, r3 = l0;

#pragma unroll
    for (int kb = 0; kb < K; kb += 32) {
        bf16x8 bfl = *(const bf16x8*)(bpl + kb);
        bf16x8 bfr = *(const bf16x8*)(bpr + kb);
        bf16x8 a0 = *(const bf16x8*)(ap + kb);
        bf16x8 a1 = *(const bf16x8*)(ap + 16 * K + kb);
        bf16x8 a2 = *(const bf16x8*)(ap + 32 * K + kb);
        bf16x8 a3 = *(const bf16x8*)(ap + 48 * K + kb);
        l0 = __builtin_amdgcn_mfma_f32_16x16x32_bf16(a0, bfl, l0, 0, 0, 0);
        r0 = __builtin_amdgcn_mfma_f32_16x16x32_bf16(a0, bfr, r0, 0, 0, 0);
        l1 = __builtin_amdgcn_mfma_f32_16x16x32_bf16(a1, bfl, l1, 0, 0, 0);
        r1 = __builtin_amdgcn_mfma_f32_16x16x32_bf16(a1, bfr, r1, 0, 0, 0);
        l2 = __builtin_amdgcn_mfma_f32_16x16x32_bf16(a2, bfl, l2, 0, 0, 0);
        r2 = __builtin_amdgcn_mfma_f32_16x16x32_bf16(a2, bfr, r2, 0, 0, 0);
        l3 = __builtin_amdgcn_mfma_f32_16x16x32_bf16(a3, bfl, l3, 0, 0, 0);
        r3 = __builtin_amdgcn_mfma_f32_16x16x32_bf16(a3, bfr, r3, 0, 0, 0);
    }

    int colg = col0 + rsub;
    float bvl = bl[colg];
    float bvr = br[colg];
    int rbase = row0 + (lane >> 4) * 4;
#pragma unroll
    for (int t = 0; t < 4; t++) {
        f32x4 al = (t == 0) ? l0 : (t == 1) ? l1 : (t == 2) ? l2 : l3;
        f32x4 ar = (t == 0) ? r0 : (t == 1) ? r1 : (t == 2) ? r2 : r3;
#pragma unroll
        for (int r = 0; r < 4; r++) {
            int row = rbase + t * 16 + r;
            if (row < M) {
                Yl[(size_t)row * NOUT + colg] = f2b(al[r] + bvl);
                Yr[(size_t)row * NOUT + colg] = f2b(ar[r] + bvr);
            }
        }
    }
}

// ---------------- layer 1 aggregation ----------------
// 1 wave/dst. Half-wave per edge: hl=lane&31 owns 4 ch (c0=hl*4, head=hl>>2).
// Head reduce = shfl_xor 1,2 (4 lanes). No online max (scores bounded);
// att pre-scaled by log2e -> exp2. ILP2: edges i+half, i+2+half.

__global__ __launch_bounds__(256) void aggregate1_kernel(
        const unsigned short* __restrict__ xl1, const unsigned short* __restrict__ xr1,
        const float* __restrict__ att1, const float* __restrict__ bias1,
        const int* __restrict__ offsets, const int* __restrict__ sorted_src,
        unsigned short* __restrict__ x1) {
    int wave = threadIdx.x >> 6;
    int lane = threadIdx.x & 63;
    int half = lane >> 5;
    int hl = lane & 31;
    int dst = blockIdx.x * 4 + wave;
    if (dst >= M_PAD) return;
    int c0 = hl * 4;
    if (dst >= N_NODES) {                  // zero pad rows for the next GEMM
        if (half == 0) {
            uint2 z; z.x = 0; z.y = 0;
            *(uint2*)(x1 + (size_t)dst * D1 + c0) = z;
        }
        return;
    }

    float xr[4], att[4];
    unpack4(*(const uint2*)(xr1 + (size_t)dst * D1 + c0), xr);
#pragma unroll
    for (int j = 0; j < 4; j++) att[j] = att1[c0 + j] * LOG2E;
    int beg = offsets[dst], end = offsets[dst + 1];

    float l = 0.f;
    float A0 = 0.f, A1 = 0.f, A2 = 0.f, A3 = 0.f;
    int i = beg;
    for (; i + 4 <= end; i += 4) {
        int sA = sorted_src[i + half];
        int sB = sorted_src[i + 2 + half];
        float vA[4], vB[4];
        unpack4(*(const uint2*)(xl1 + (size_t)sA * D1 + c0), vA);
        unpack4(*(const uint2*)(xl1 + (size_t)sB * D1 + c0), vB);
        float pA = att[0] * lrelu(vA[0] + xr[0]) + att[1] * lrelu(vA[1] + xr[1])
                 + att[2] * lrelu(vA[2] + xr[2]) + att[3] * lrelu(vA[3] + xr[3]);
        float pB = att[0] * lrelu(vB[0] + xr[0]) + att[1] * lrelu(vB[1] + xr[1])
                 + att[2] * lrelu(vB[2] + xr[2]) + att[3] * lrelu(vB[3] + xr[3]);
        pA += __shfl_xor(pA, 1); pB += __shfl_xor(pB, 1);
        pA += __shfl_xor(pA, 2); pB += __shfl_xor(pB, 2);
        float wA = EXP2F(pA), wB = EXP2F(pB);
        l += wA + wB;
        A0 += wA * vA[0] + wB * vB[0];
        A1 += wA * vA[1] + wB * vB[1];
        A2 += wA * vA[2] + wB * vB[2];
        A3 += wA * vA[3] + wB * vB[3];
    }
    for (; i + 2 <= end; i += 2) {
        int sA = sorted_src[i + half];
        float vA[4];
        unpack4(*(const uint2*)(xl1 + (size_t)sA * D1 + c0), vA);
        float pA = att[0] * lrelu(vA[0] + xr[0]) + att[1] * lrelu(vA[1] + xr[1])
                 + att[2] * lrelu(vA[2] + xr[2]) + att[3] * lrelu(vA[3] + xr[3]);
        pA += __shfl_xor(pA, 1);
        pA += __shfl_xor(pA, 2);
        float wA = EXP2F(pA);
        l += wA;
        A0 += wA * vA[0]; A1 += wA * vA[1]; A2 += wA * vA[2]; A3 += wA * vA[3];
    }
    if (i < end && half == 0) {
        int sA = sorted_src[i];
        float vA[4];
        unpack4(*(const uint2*)(xl1 + (size_t)sA * D1 + c0), vA);
        float pA = att[0] * lrelu(vA[0] + xr[0]) + att[1] * lrelu(vA[1] + xr[1])
                 + att[2] * lrelu(vA[2] + xr[2]) + att[3] * lrelu(vA[3] + xr[3]);
        pA += __shfl_xor(pA, 1);
        pA += __shfl_xor(pA, 2);
        float wA = EXP2F(pA);
        l += wA;
        A0 += wA * vA[0]; A1 += wA * vA[1]; A2 += wA * vA[2]; A3 += wA * vA[3];
    }
    // merge halves
    l  += __shfl_xor(l, 32);
    A0 += __shfl_xor(A0, 32);
    A1 += __shfl_xor(A1, 32);
    A2 += __shfl_xor(A2, 32);
    A3 += __shfl_xor(A3, 32);
    if (half == 0) {
        float inv = 1.f / l;
        unsigned short o0 = f2b(fmaxf(A0 * inv + bias1[c0 + 0], 0.f));
        unsigned short o1 = f2b(fmaxf(A1 * inv + bias1[c0 + 1], 0.f));
        unsigned short o2 = f2b(fmaxf(A2 * inv + bias1[c0 + 2], 0.f));
        unsigned short o3 = f2b(fmaxf(A3 * inv + bias1[c0 + 3], 0.f));
        uint2 o;
        o.x = (unsigned int)o0 | ((unsigned int)o1 << 16);
        o.y = (unsigned int)o2 | ((unsigned int)o3 << 16);
        *(uint2*)(x1 + (size_t)dst * D1 + c0) = o;
    }
}

// ---------------- layer 2 aggregation ----------------
// 1 wave/dst. Half-wave per edge: hl owns 8 ch (c0=hl*8).
// Reduce over 32 lanes = shfl_xor 1..16. No online max; exp2. ILP2.

__global__ __launch_bounds__(256) void aggregate2_kernel(
        const unsigned short* __restrict__ xl2, const unsigned short* __restrict__ xr2,
        const float* __restrict__ att2, const float* __restrict__ bias2,
        const int* __restrict__ offsets, const int* __restrict__ sorted_src,
        float* __restrict__ x2) {
    int wave = threadIdx.x >> 6;
    int lane = threadIdx.x & 63;
    int half = lane >> 5;
    int hl = lane & 31;
    int dst = blockIdx.x * 4 + wave;
    if (dst >= N_NODES) return;
    int c0 = hl * 8;

    float xr[8], att[8];
    unpack8(*(const uint4*)(xr2 + (size_t)dst * D2 + c0), xr);
#pragma unroll
    for (int j = 0; j < 8; j++) att[j] = att2[c0 + j] * LOG2E;
    int beg = offsets[dst], end = offsets[dst + 1];

    float l = 0.f;
    float acc[8];
#pragma unroll
    for (int j = 0; j < 8; j++) acc[j] = 0.f;

    int i = beg;
    for (; i + 4 <= end; i += 4) {
        int sA = sorted_src[i + half];
        int sB = sorted_src[i + 2 + half];
        float vA[8], vB[8];
        unpack8(*(const uint4*)(xl2 + (size_t)sA * D2 + c0), vA);
        unpack8(*(const uint4*)(xl2 + (size_t)sB * D2 + c0), vB);
        float pA = 0.f, pB = 0.f;
#pragma unroll
        for (int j = 0; j < 8; j++) pA = fmaf(att[j], lrelu(vA[j] + xr[j]), pA);
#pragma unroll
        for (int j = 0; j < 8; j++) pB = fmaf(att[j], lrelu(vB[j] + xr[j]), pB);
        pA += __shfl_xor(pA, 1);  pB += __shfl_xor(pB, 1);
        pA += __shfl_xor(pA, 2);  pB += __shfl_xor(pB, 2);
        pA += __shfl_xor(pA, 4);  pB += __shfl_xor(pB, 4);
        pA += __shfl_xor(pA, 8);  pB += __shfl_xor(pB, 8);
        pA += __shfl_xor(pA, 16); pB += __shfl_xor(pB, 16);
        float wA = EXP2F(pA), wB = EXP2F(pB);
        l += wA + wB;
#pragma unroll
        for (int j = 0; j < 8; j++) acc[j] += wA * vA[j] + wB * vB[j];
    }
    for (; i + 2 <= end; i += 2) {
        int sA = sorted_src[i + half];
        float vA[8];
        unpack8(*(const uint4*)(xl2 + (size_t)sA * D2 + c0), vA);
        float pA = 0.f;
#pragma unroll
        for (int j = 0; j < 8; j++) pA = fmaf(att[j], lrelu(vA[j] + xr[j]), pA);
        pA += __shfl_xor(pA, 1);
        pA += __shfl_xor(pA, 2);
        pA += __shfl_xor(pA, 4);
        pA += __shfl_xor(pA, 8);
        pA += __shfl_xor(pA, 16);
        float wA = EXP2F(pA);
        l += wA;
#pragma unroll
        for (int j = 0; j < 8; j++) acc[j] += wA * vA[j];
    }
    if (i < end && half == 0) {
        int sA = sorted_src[i];
        float vA[8];
        unpack8(*(const uint4*)(xl2 + (size_t)sA * D2 + c0), vA);
        float pA = 0.f;
#pragma unroll
        for (int j = 0; j < 8; j++) pA = fmaf(att[j], lrelu(vA[j] + xr[j]), pA);
        pA += __shfl_xor(pA, 1);
        pA += __shfl_xor(pA, 2);
        pA += __shfl_xor(pA, 4);
        pA += __shfl_xor(pA, 8);
        pA += __shfl_xor(pA, 16);
        float wA = EXP2F(pA);
        l += wA;
#pragma unroll
        for (int j = 0; j < 8; j++) acc[j] += wA * vA[j];
    }
    // merge halves
    l += __shfl_xor(l, 32);
#pragma unroll
    for (int j = 0; j < 8; j++) acc[j] += __shfl_xor(acc[j], 32);
    if (half == 0) {
        float inv = 1.f / l;
        float4 o0, o1;
        o0.x = acc[0] * inv + bias2[c0 + 0];
        o0.y = acc[1] * inv + bias2[c0 + 1];
        o0.z = acc[2] * inv + bias2[c0 + 2];
        o0.w = acc[3] * inv + bias2[c0 + 3];
        o1.x = acc[4] * inv + bias2[c0 + 4];
        o1.y = acc[5] * inv + bias2[c0 + 5];
        o1.z = acc[6] * inv + bias2[c0 + 6];
        o1.w = acc[7] * inv + bias2[c0 + 7];
        *(float4*)(x2 + (size_t)dst * D2 + c0) = o0;
        *(float4*)(x2 + (size_t)dst * D2 + c0 + 4) = o1;
    }
}

// ---------------- classifier ----------------

__global__ __launch_bounds__(256) void classifier_kernel(
        const float* __restrict__ vanilla_x, const float* __restrict__ x2,
        const int* __restrict__ a1_raw, const int* __restrict__ a2_raw,
        const float* __restrict__ Wc, const float* __restrict__ bc,
        float* __restrict__ out) {
    int b = blockIdx.x;
    int t = threadIdx.x;

    // detect int64 vs int32 storage of index arrays
    __shared__ int stride_s;
    if (t == 0) {
        bool i64 = true;
        for (int i = 1; i < 63; i += 2) i64 = i64 && (a1_raw[i] == 0);
        stride_s = i64 ? 2 : 1;
    }
    __syncthreads();
    int stride = stride_s;
    int a1 = a1_raw[(long)b * stride];
    int a2 = a2_raw[(long)b * stride];

    float s = vanilla_x[a1 * IN_CH + t] * Wc[t]
            + vanilla_x[a2 * IN_CH + t] * Wc[IN_CH + t]
            + x2[a1 * D2 + t] * Wc[2 * IN_CH + t]
            + x2[a2 * D2 + t] * Wc[3 * IN_CH + t];
    s += __shfl_xor(s, 1);
    s += __shfl_xor(s, 2);
    s += __shfl_xor(s, 4);
    s += __shfl_xor(s, 8);
    s += __shfl_xor(s, 16);
    s += __shfl_xor(s, 32);
    __shared__ float part[4];
    if ((t & 63) == 0) part[t >> 6] = s;
    __syncthreads();
    if (t == 0) out[b] = part[0] + part[1] + part[2] + part[3] + bc[0];
}

// ---------------- launch ----------------

extern "C" void kernel_launch(void* const* d_in, const int* in_sizes, int n_in,
                              void* d_out, int out_size, void* d_ws, size_t ws_size,
                              hipStream_t stream) {
    const float* gnn_x     = (const float*)d_in[0];
    const float* vanilla_x = (const float*)d_in[1];
    const int*   edge_src  = (const int*)d_in[2];
    const int*   edge_dst  = (const int*)d_in[3];
    const int*   a1_idx    = (const int*)d_in[4];
    const int*   a2_idx    = (const int*)d_in[5];
    const float* Wl1   = (const float*)d_in[6];
    const float* bl1   = (const float*)d_in[7];
    const float* Wr1   = (const float*)d_in[8];
    const float* br1   = (const float*)d_in[9];
    const float* att1  = (const float*)d_in[10];
    const float* bias1 = (const float*)d_in[11];
    const float* Wl2   = (const float*)d_in[12];
    const float* bl2   = (const float*)d_in[13];
    const float* Wr2   = (const float*)d_in[14];
    const float* br2   = (const float*)d_in[15];
    const float* att2  = (const float*)d_in[16];
    const float* bias2 = (const float*)d_in[17];
    const float* Wc    = (const float*)d_in[18];
    const float* bc    = (const float*)d_in[19];
    float* out = (float*)d_out;

    // workspace layout
    char* p = (char*)d_ws;
    unsigned short* xb   = (unsigned short*)p; p += (size_t)M_PAD * IN_CH * 2;
    unsigned short* x1b  = (unsigned short*)p; p += (size_t)M_PAD * D1 * 2;
    unsigned short* xl1b = (unsigned short*)p; p += (size_t)N_NODES * D1 * 2;
    unsigned short* xr1b = (unsigned short*)p; p += (size_t)N_NODES * D1 * 2;
    unsigned short* xl2b = (unsigned short*)p; p += (size_t)N_NODES * D2 * 2;
    unsigned short* xr2b = (unsigned short*)p; p += (size_t)N_NODES * D2 * 2;
    unsigned short* wt1l = (unsigned short*)p; p += (size_t)D1 * IN_CH * 2;
    unsigned short* wt1r = (unsigned short*)p; p += (size_t)D1 * IN_CH * 2;
    unsigned short* wt2l = (unsigned short*)p; p += (size_t)D2 * D1 * 2;
    unsigned short* wt2r = (unsigned short*)p; p += (size_t)D2 * D1 * 2;
    float* x2 = (float*)p; p += (size_t)N_NODES * D2 * 4;
    int* count      = (int*)p; p += (size_t)N_NODES * 4;
    int* offsets    = (int*)p; p += (size_t)(N_NODES + 4) * 4;
    int* rank       = (int*)p; p += (size_t)ET * 4;
    int* sorted_src = (int*)p; p += (size_t)ET * 4;

    hipMemsetAsync(count, 0, (size_t)N_NODES * sizeof(int), stream);

    prep_kernel<<<XCONV_BLOCKS + WCONV_BLOCKS + HIST_BLOCKS, 256, 0, stream>>>(
        gnn_x, Wl1, Wr1, Wl2, Wr2, edge_dst,
        xb, wt1l, wt1r, wt2l, wt2r, count, rank);
    scan_kernel<<<1, 1024, 0, stream>>>(count, offsets);
    scatter_kernel<<<HIST_BLOCKS, 256, 0, stream>>>(
        edge_src, edge_dst, rank, offsets, sorted_src);

    // layer 1: fused dual GEMM + aggregation
    dim3 g1(M_PAD / 64, D1 / 64);   // (313, 2)
    dual_gemm_mfma_kernel<IN_CH><<<g1, 256, 0, stream>>>(
        xb, wt1l, wt1r, bl1, br1, xl1b, xr1b, N_NODES, D1);
    aggregate1_kernel<<<M_PAD / 4, 256, 0, stream>>>(
        xl1b, xr1b, att1, bias1, offsets, sorted_src, x1b);

    // layer 2
    dim3 g2(M_PAD / 64, D2 / 64);   // (313, 4)
    dual_gemm_mfma_kernel<D1><<<g2, 256, 0, stream>>>(
        x1b, wt2l, wt2r, bl2, br2, xl2b, xr2b, N_NODES, D2);
    aggregate2_kernel<<<(N_NODES + 3) / 4, 256, 0, stream>>>(
        xl2b, xr2b, att2, bias2, offsets, sorted_src, x2);

    // classifier
    classifier_kernel<<<BPAIRS, 256, 0, stream>>>(
        vanilla_x, x2, a1_idx, a2_idx, Wc, bc, out);
}

// Round 5
// 298.440 us; speedup vs baseline: 1.6713x; 1.0013x over previous
//
#include <hip/hip_runtime.h>
#include <math.h>

#define N_NODES 20000
#define M_PAD   20032            // 64-row padded for MFMA row tiles
#define E_EDGES 640000
#define ET (E_EDGES + N_NODES)   // edges + self loops
#define IN_CH 256
#define D1 128                   // H1*C1 = 8*16
#define D2 256                   // H2*C2 = 1*256
#define BPAIRS 4096
#define NEG 0.2f
#define LOG2E 1.4426950408889634f

#define XCONV_BLOCKS 5008        // M_PAD*IN_CH/4/256
#define WCONV_BLOCKS 512         // 131072/256
#define HIST_BLOCKS  ((ET + 255) / 256)

#if __has_builtin(__builtin_amdgcn_exp2f)
#define EXP2F(x) __builtin_amdgcn_exp2f(x)
#else
#define EXP2F(x) exp2f(x)
#endif

typedef __bf16 bf16x8 __attribute__((ext_vector_type(8)));
typedef float  f32x4  __attribute__((ext_vector_type(4)));
typedef float  f32x2  __attribute__((ext_vector_type(2)));

__device__ __forceinline__ unsigned short f2b(float f) {
    unsigned int u = __float_as_uint(f);
    unsigned int r = u + 0x7FFFu + ((u >> 16) & 1u);   // RNE
    return (unsigned short)(r >> 16);
}
// packed bf16 pair -> f32x2 (2 instrs)
__device__ __forceinline__ f32x2 up2(unsigned int u) {
    f32x2 r;
    r.x = __uint_as_float(u << 16);
    r.y = __uint_as_float(u & 0xFFFF0000u);
    return r;
}
// lrelu on packed pair: max(s, 0.2*s) -> v_pk_mul + v_pk_max
__device__ __forceinline__ f32x2 lrelu2(f32x2 s) {
    return __builtin_elementwise_max(s, s * NEG);
}

// ---------------- fused prep: x->bf16, weights->bf16^T, dst histogram -------

__global__ void prep_kernel(
        const float* __restrict__ gnn_x,
        const float* __restrict__ Wl1, const float* __restrict__ Wr1,
        const float* __restrict__ Wl2, const float* __restrict__ Wr2,
        const int* __restrict__ edge_dst,
        unsigned short* __restrict__ xb,
        unsigned short* __restrict__ wt1l, unsigned short* __restrict__ wt1r,
        unsigned short* __restrict__ wt2l, unsigned short* __restrict__ wt2r,
        int* __restrict__ count, int* __restrict__ rank) {
    int bid = blockIdx.x;
    if (bid < XCONV_BLOCKS) {
        int e0 = (bid * 256 + threadIdx.x) * 4;
        int row = e0 >> 8;                 // / IN_CH
        ushort4 o;
        if (row < N_NODES) {
            float4 v = *(const float4*)(gnn_x + e0);
            o.x = f2b(v.x); o.y = f2b(v.y); o.z = f2b(v.z); o.w = f2b(v.w);
        } else {
            o.x = o.y = o.z = o.w = 0;
        }
        *(ushort4*)(xb + e0) = o;
    } else if (bid < XCONV_BLOCKS + WCONV_BLOCKS) {
        int idx = (bid - XCONV_BLOCKS) * 256 + threadIdx.x;  // 0..131071
        int seg = idx >> 15;               // 4 segments of 32768
        int r = idx & 32767;
        const float* W;
        unsigned short* Wt;
        int k, n, K;
        if (seg < 2) {                     // layer1: K=256, N=128
            W = seg ? Wr1 : Wl1; Wt = seg ? wt1r : wt1l;
            k = r >> 7; n = r & 127; K = IN_CH;
        } else {                           // layer2: K=128, N=256
            W = (seg & 1) ? Wr2 : Wl2; Wt = (seg & 1) ? wt2r : wt2l;
            k = r >> 8; n = r & 255; K = D1;
        }
        Wt[n * K + k] = f2b(W[r]);
    } else {
        int e = (bid - XCONV_BLOCKS - WCONV_BLOCKS) * 256 + threadIdx.x;
        if (e >= ET) return;
        int dst = (e < E_EDGES) ? edge_dst[e] : (e - E_EDGES);
        rank[e] = atomicAdd(&count[dst], 1);
    }
}

// ---------------- CSR scan + scatter ----------------

__global__ __launch_bounds__(1024) void scan_kernel(const int* __restrict__ count,
                                                    int* __restrict__ offsets) {
    const int PER = 20;
    int t = threadIdx.x;
    int base = t * PER;
    int local[PER];
    int sum = 0;
#pragma unroll
    for (int i = 0; i < PER; i++) {
        int idx = base + i;
        int v = (idx < N_NODES) ? count[idx] : 0;
        local[i] = sum;
        sum += v;
    }
    int lane = t & 63, wave = t >> 6;
    int s = sum;
#pragma unroll
    for (int off = 1; off < 64; off <<= 1) {
        int x = __shfl_up(s, off);
        if (lane >= off) s += x;
    }
    __shared__ int wsum[16];
    __shared__ int wpre[16];
    if (lane == 63) wsum[wave] = s;
    __syncthreads();
    if (t == 0) {
        int acc = 0;
        for (int w = 0; w < 16; w++) { wpre[w] = acc; acc += wsum[w]; }
        offsets[N_NODES] = acc;  // == ET
    }
    __syncthreads();
    int thread_excl = wpre[wave] + (s - sum);
#pragma unroll
    for (int i = 0; i < PER; i++) {
        int idx = base + i;
        if (idx < N_NODES) offsets[idx] = thread_excl + local[i];
    }
}

__global__ void scatter_kernel(const int* __restrict__ edge_src,
                               const int* __restrict__ edge_dst,
                               const int* __restrict__ rank,
                               const int* __restrict__ offsets,
                               int* __restrict__ sorted_src) {
    int e = blockIdx.x * blockDim.x + threadIdx.x;
    if (e >= ET) return;
    int dst = (e < E_EDGES) ? edge_dst[e] : (e - E_EDGES);
    int src = (e < E_EDGES) ? edge_src[e] : (e - E_EDGES);
    sorted_src[offsets[dst] + rank[e]] = src;
}

// ---------------- dual MFMA GEMM: Yl = A@Wl^T+bl, Yr = A@Wr^T+br -------------

template <int K>
__global__ __launch_bounds__(256) void dual_gemm_mfma_kernel(
        const unsigned short* __restrict__ A,    // M_PAD x K
        const unsigned short* __restrict__ Wtl,  // NOUT x K
        const unsigned short* __restrict__ Wtr,  // NOUT x K
        const float* __restrict__ bl, const float* __restrict__ br,
        unsigned short* __restrict__ Yl, unsigned short* __restrict__ Yr,
        int M, int NOUT) {
    int wave = threadIdx.x >> 6;
    int lane = threadIdx.x & 63;
    int row0 = blockIdx.x * 64;
    int col0 = (blockIdx.y * 4 + wave) * 16;
    int rsub = lane & 15;
    int koff = (lane >> 4) * 8;

    const unsigned short* ap  = A   + (size_t)(row0 + rsub) * K + koff;
    const unsigned short* bpl = Wtl + (size_t)(col0 + rsub) * K + koff;
    const unsigned short* bpr = Wtr + (size_t)(col0 + rsub) * K + koff;

    f32x4 l0 = {0.f, 0.f, 0.f, 0.f};
    f32x4 l1 = l0, l2 = l0, l3 = l0, r0 = l0, r1 = l0, r2 = l0, r3 = l0;

#pragma unroll
    for (int kb = 0; kb < K; kb += 32) {
        bf16x8 bfl = *(const bf16x8*)(bpl + kb);
        bf16x8 bfr = *(const bf16x8*)(bpr + kb);
        bf16x8 a0 = *(const bf16x8*)(ap + kb);
        bf16x8 a1 = *(const bf16x8*)(ap + 16 * K + kb);
        bf16x8 a2 = *(const bf16x8*)(ap + 32 * K + kb);
        bf16x8 a3 = *(const bf16x8*)(ap + 48 * K + kb);
        l0 = __builtin_amdgcn_mfma_f32_16x16x32_bf16(a0, bfl, l0, 0, 0, 0);
        r0 = __builtin_amdgcn_mfma_f32_16x16x32_bf16(a0, bfr, r0, 0, 0, 0);
        l1 = __builtin_amdgcn_mfma_f32_16x16x32_bf16(a1, bfl, l1, 0, 0, 0);
        r1 = __builtin_amdgcn_mfma_f32_16x16x32_bf16(a1, bfr, r1, 0, 0, 0);
        l2 = __builtin_amdgcn_mfma_f32_16x16x32_bf16(a2, bfl, l2, 0, 0, 0);
        r2 = __builtin_amdgcn_mfma_f32_16x16x32_bf16(a2, bfr, r2, 0, 0, 0);
        l3 = __builtin_amdgcn_mfma_f32_16x16x32_bf16(a3, bfl, l3, 0, 0, 0);
        r3 = __builtin_amdgcn_mfma_f32_16x16x32_bf16(a3, bfr, r3, 0, 0, 0);
    }

    int colg = col0 + rsub;
    float bvl = bl[colg];
    float bvr = br[colg];
    int rbase = row0 + (lane >> 4) * 4;
#pragma unroll
    for (int t = 0; t < 4; t++) {
        f32x4 al = (t == 0) ? l0 : (t == 1) ? l1 : (t == 2) ? l2 : l3;
        f32x4 ar = (t == 0) ? r0 : (t == 1) ? r1 : (t == 2) ? r2 : r3;
#pragma unroll
        for (int r = 0; r < 4; r++) {
            int row = rbase + t * 16 + r;
            if (row < M) {
                Yl[(size_t)row * NOUT + colg] = f2b(al[r] + bvl);
                Yr[(size_t)row * NOUT + colg] = f2b(ar[r] + bvr);
            }
        }
    }
}

// ---------------- layer 1 aggregation ----------------
// 1 wave/dst. QUARTER-wave per edge: q=lane>>4, ql=lane&15 owns 8 ch
// (c0=ql*8, head=ql>>1, 2 lanes/head). 4 edges per wave-instruction.
// Head reduce = shfl_xor 1. Pipelined prefetch of next 4 edges. Masked tail.

__global__ __launch_bounds__(256) void aggregate1_kernel(
        const unsigned short* __restrict__ xl1, const unsigned short* __restrict__ xr1,
        const float* __restrict__ att1, const float* __restrict__ bias1,
        const int* __restrict__ offsets, const int* __restrict__ sorted_src,
        unsigned short* __restrict__ x1) {
    int wave = threadIdx.x >> 6;
    int lane = threadIdx.x & 63;
    int q = lane >> 4;                 // quarter 0..3
    int ql = lane & 15;
    int dst = blockIdx.x * 4 + wave;
    if (dst >= M_PAD) return;
    int c0 = ql * 8;
    if (dst >= N_NODES) {              // zero pad rows for the next GEMM
        if (q == 0) {
            uint4 z; z.x = z.y = z.z = z.w = 0;
            *(uint4*)(x1 + (size_t)dst * D1 + c0) = z;
        }
        return;
    }

    uint4 xu = *(const uint4*)(xr1 + (size_t)dst * D1 + c0);
    f32x2 xr[4] = {up2(xu.x), up2(xu.y), up2(xu.z), up2(xu.w)};
    float4 aa0 = *(const float4*)(att1 + c0);
    float4 aa1 = *(const float4*)(att1 + c0 + 4);
    f32x2 att[4];
    att[0].x = aa0.x * LOG2E; att[0].y = aa0.y * LOG2E;
    att[1].x = aa0.z * LOG2E; att[1].y = aa0.w * LOG2E;
    att[2].x = aa1.x * LOG2E; att[2].y = aa1.y * LOG2E;
    att[3].x = aa1.z * LOG2E; att[3].y = aa1.w * LOG2E;

    int beg = offsets[dst], end = offsets[dst + 1];
    const unsigned short* base = xl1 + c0;

    float l = 0.f;
    f32x2 acc[4] = {{0.f,0.f},{0.f,0.f},{0.f,0.f},{0.f,0.f}};

    int i = beg;
    int s0 = sorted_src[min(i + q, end - 1)];
    uint4 g0 = *(const uint4*)(base + (size_t)s0 * D1);
    while (true) {
        int inext = i + 4;
        bool more = inext < end;
        uint4 g1;
        if (more) {
            int s1 = sorted_src[min(inext + q, end - 1)];
            g1 = *(const uint4*)(base + (size_t)s1 * D1);
        }
        bool act = (i + q) < end;
        f32x2 v0 = up2(g0.x), v1 = up2(g0.y), v2 = up2(g0.z), v3 = up2(g0.w);
        f32x2 p2 = att[0] * lrelu2(v0 + xr[0]);
        p2 += att[1] * lrelu2(v1 + xr[1]);
        p2 += att[2] * lrelu2(v2 + xr[2]);
        p2 += att[3] * lrelu2(v3 + xr[3]);
        float p = p2.x + p2.y;
        p += __shfl_xor(p, 1);          // head reduce (2 lanes/head)
        float w = act ? EXP2F(p) : 0.f;
        l += w;
        acc[0] += w * v0; acc[1] += w * v1; acc[2] += w * v2; acc[3] += w * v3;
        if (!more) break;
        i = inext; g0 = g1;
    }
    // merge quarters (same channels live in lanes ql, ql+16, ql+32, ql+48)
    l += __shfl_xor(l, 16);
    l += __shfl_xor(l, 32);
#pragma unroll
    for (int j = 0; j < 4; j++) {
        f32x2 t;
        t.x = __shfl_xor(acc[j].x, 16); t.y = __shfl_xor(acc[j].y, 16);
        acc[j] += t;
        t.x = __shfl_xor(acc[j].x, 32); t.y = __shfl_xor(acc[j].y, 32);
        acc[j] += t;
    }
    if (q == 0) {
        float inv = 1.f / l;
        float4 bb0 = *(const float4*)(bias1 + c0);
        float4 bb1 = *(const float4*)(bias1 + c0 + 4);
        unsigned short o[8];
        o[0] = f2b(fmaxf(acc[0].x * inv + bb0.x, 0.f));
        o[1] = f2b(fmaxf(acc[0].y * inv + bb0.y, 0.f));
        o[2] = f2b(fmaxf(acc[1].x * inv + bb0.z, 0.f));
        o[3] = f2b(fmaxf(acc[1].y * inv + bb0.w, 0.f));
        o[4] = f2b(fmaxf(acc[2].x * inv + bb1.x, 0.f));
        o[5] = f2b(fmaxf(acc[2].y * inv + bb1.y, 0.f));
        o[6] = f2b(fmaxf(acc[3].x * inv + bb1.z, 0.f));
        o[7] = f2b(fmaxf(acc[3].y * inv + bb1.w, 0.f));
        uint4 ov;
        ov.x = (unsigned int)o[0] | ((unsigned int)o[1] << 16);
        ov.y = (unsigned int)o[2] | ((unsigned int)o[3] << 16);
        ov.z = (unsigned int)o[4] | ((unsigned int)o[5] << 16);
        ov.w = (unsigned int)o[6] | ((unsigned int)o[7] << 16);
        *(uint4*)(x1 + (size_t)dst * D1 + c0) = ov;
    }
}

// ---------------- layer 2 aggregation ----------------
// 1 wave/dst. Half-wave per edge: hl=lane&31 owns 8 ch (c0=hl*8).
// ILP2 per half (edges i+half, i+2+half) + pipelined prefetch. Masked tail.

__global__ __launch_bounds__(256) void aggregate2_kernel(
        const unsigned short* __restrict__ xl2, const unsigned short* __restrict__ xr2,
        const float* __restrict__ att2, const float* __restrict__ bias2,
        const int* __restrict__ offsets, const int* __restrict__ sorted_src,
        float* __restrict__ x2) {
    int wave = threadIdx.x >> 6;
    int lane = threadIdx.x & 63;
    int half = lane >> 5;
    int hl = lane & 31;
    int dst = blockIdx.x * 4 + wave;
    if (dst >= N_NODES) return;
    int c0 = hl * 8;

    uint4 xu = *(const uint4*)(xr2 + (size_t)dst * D2 + c0);
    f32x2 xr[4] = {up2(xu.x), up2(xu.y), up2(xu.z), up2(xu.w)};
    float4 aa0 = *(const float4*)(att2 + c0);
    float4 aa1 = *(const float4*)(att2 + c0 + 4);
    f32x2 att[4];
    att[0].x = aa0.x * LOG2E; att[0].y = aa0.y * LOG2E;
    att[1].x = aa0.z * LOG2E; att[1].y = aa0.w * LOG2E;
    att[2].x = aa1.x * LOG2E; att[2].y = aa1.y * LOG2E;
    att[3].x = aa1.z * LOG2E; att[3].y = aa1.w * LOG2E;

    int beg = offsets[dst], end = offsets[dst + 1];
    const unsigned short* base = xl2 + c0;

    float l = 0.f;
    f32x2 acc[4] = {{0.f,0.f},{0.f,0.f},{0.f,0.f},{0.f,0.f}};

    int i = beg;
    int sA = sorted_src[min(i + half, end - 1)];
    int sB = sorted_src[min(i + 2 + half, end - 1)];
    uint4 gA = *(const uint4*)(base + (size_t)sA * D2);
    uint4 gB = *(const uint4*)(base + (size_t)sB * D2);
    while (true) {
        int inext = i + 4;
        bool more = inext < end;
        uint4 gA2, gB2;
        if (more) {
            int sA2 = sorted_src[min(inext + half, end - 1)];
            int sB2 = sorted_src[min(inext + 2 + half, end - 1)];
            gA2 = *(const uint4*)(base + (size_t)sA2 * D2);
            gB2 = *(const uint4*)(base + (size_t)sB2 * D2);
        }
        bool actA = (i + half) < end;
        bool actB = (i + 2 + half) < end;

        f32x2 vA0 = up2(gA.x), vA1 = up2(gA.y), vA2 = up2(gA.z), vA3 = up2(gA.w);
        f32x2 vB0 = up2(gB.x), vB1 = up2(gB.y), vB2 = up2(gB.z), vB3 = up2(gB.w);
        f32x2 pA2 = att[0] * lrelu2(vA0 + xr[0]);
        f32x2 pB2 = att[0] * lrelu2(vB0 + xr[0]);
        pA2 += att[1] * lrelu2(vA1 + xr[1]);
        pB2 += att[1] * lrelu2(vB1 + xr[1]);
        pA2 += att[2] * lrelu2(vA2 + xr[2]);
        pB2 += att[2] * lrelu2(vB2 + xr[2]);
        pA2 += att[3] * lrelu2(vA3 + xr[3]);
        pB2 += att[3] * lrelu2(vB3 + xr[3]);
        float pA = pA2.x + pA2.y;
        float pB = pB2.x + pB2.y;
        pA += __shfl_xor(pA, 1);  pB += __shfl_xor(pB, 1);
        pA += __shfl_xor(pA, 2);  pB += __shfl_xor(pB, 2);
        pA += __shfl_xor(pA, 4);  pB += __shfl_xor(pB, 4);
        pA += __shfl_xor(pA, 8);  pB += __shfl_xor(pB, 8);
        pA += __shfl_xor(pA, 16); pB += __shfl_xor(pB, 16);
        float wA = actA ? EXP2F(pA) : 0.f;
        float wB = actB ? EXP2F(pB) : 0.f;
        l += wA + wB;
        acc[0] += wA * vA0 + wB * vB0;
        acc[1] += wA * vA1 + wB * vB1;
        acc[2] += wA * vA2 + wB * vB2;
        acc[3] += wA * vA3 + wB * vB3;
        if (!more) break;
        i = inext; gA = gA2; gB = gB2;
    }
    // merge halves
    l += __shfl_xor(l, 32);
#pragma unroll
    for (int j = 0; j < 4; j++) {
        f32x2 t;
        t.x = __shfl_xor(acc[j].x, 32); t.y = __shfl_xor(acc[j].y, 32);
        acc[j] += t;
    }
    if (half == 0) {
        float inv = 1.f / l;
        float4 bb0 = *(const float4*)(bias2 + c0);
        float4 bb1 = *(const float4*)(bias2 + c0 + 4);
        float4 o0, o1;
        o0.x = acc[0].x * inv + bb0.x;
        o0.y = acc[0].y * inv + bb0.y;
        o0.z = acc[1].x * inv + bb0.z;
        o0.w = acc[1].y * inv + bb0.w;
        o1.x = acc[2].x * inv + bb1.x;
        o1.y = acc[2].y * inv + bb1.y;
        o1.z = acc[3].x * inv + bb1.z;
        o1.w = acc[3].y * inv + bb1.w;
        *(float4*)(x2 + (size_t)dst * D2 + c0) = o0;
        *(float4*)(x2 + (size_t)dst * D2 + c0 + 4) = o1;
    }
}

// ---------------- classifier ----------------

__global__ __launch_bounds__(256) void classifier_kernel(
        const float* __restrict__ vanilla_x, const float* __restrict__ x2,
        const int* __restrict__ a1_raw, const int* __restrict__ a2_raw,
        const float* __restrict__ Wc, const float* __restrict__ bc,
        float* __restrict__ out) {
    int b = blockIdx.x;
    int t = threadIdx.x;

    // detect int64 vs int32 storage of index arrays
    __shared__ int stride_s;
    if (t == 0) {
        bool i64 = true;
        for (int i = 1; i < 63; i += 2) i64 = i64 && (a1_raw[i] == 0);
        stride_s = i64 ? 2 : 1;
    }
    __syncthreads();
    int stride = stride_s;
    int a1 = a1_raw[(long)b * stride];
    int a2 = a2_raw[(long)b * stride];

    float s = vanilla_x[a1 * IN_CH + t] * Wc[t]
            + vanilla_x[a2 * IN_CH + t] * Wc[IN_CH + t]
            + x2[a1 * D2 + t] * Wc[2 * IN_CH + t]
            + x2[a2 * D2 + t] * Wc[3 * IN_CH + t];
    s += __shfl_xor(s, 1);
    s += __shfl_xor(s, 2);
    s += __shfl_xor(s, 4);
    s += __shfl_xor(s, 8);
    s += __shfl_xor(s, 16);
    s += __shfl_xor(s, 32);
    __shared__ float part[4];
    if ((t & 63) == 0) part[t >> 6] = s;
    __syncthreads();
    if (t == 0) out[b] = part[0] + part[1] + part[2] + part[3] + bc[0];
}

// ---------------- launch ----------------

extern "C" void kernel_launch(void* const* d_in, const int* in_sizes, int n_in,
                              void* d_out, int out_size, void* d_ws, size_t ws_size,
                              hipStream_t stream) {
    const float* gnn_x     = (const float*)d_in[0];
    const float* vanilla_x = (const float*)d_in[1];
    const int*   edge_src  = (const int*)d_in[2];
    const int*   edge_dst  = (const int*)d_in[3];
    const int*   a1_idx    = (const int*)d_in[4];
    const int*   a2_idx    = (const int*)d_in[5];
    const float* Wl1   = (const float*)d_in[6];
    const float* bl1   = (const float*)d_in[7];
    const float* Wr1   = (const float*)d_in[8];
    const float* br1   = (const float*)d_in[9];
    const float* att1  = (const float*)d_in[10];
    const float* bias1 = (const float*)d_in[11];
    const float* Wl2   = (const float*)d_in[12];
    const float* bl2   = (const float*)d_in[13];
    const float* Wr2   = (const float*)d_in[14];
    const float* br2   = (const float*)d_in[15];
    const float* att2  = (const float*)d_in[16];
    const float* bias2 = (const float*)d_in[17];
    const float* Wc    = (const float*)d_in[18];
    const float* bc    = (const float*)d_in[19];
    float* out = (float*)d_out;

    // workspace layout
    char* p = (char*)d_ws;
    unsigned short* xb   = (unsigned short*)p; p += (size_t)M_PAD * IN_CH * 2;
    unsigned short* x1b  = (unsigned short*)p; p += (size_t)M_PAD * D1 * 2;
    unsigned short* xl1b = (unsigned short*)p; p += (size_t)N_NODES * D1 * 2;
    unsigned short* xr1b = (unsigned short*)p; p += (size_t)N_NODES * D1 * 2;
    unsigned short* xl2b = (unsigned short*)p; p += (size_t)N_NODES * D2 * 2;
    unsigned short* xr2b = (unsigned short*)p; p += (size_t)N_NODES * D2 * 2;
    unsigned short* wt1l = (unsigned short*)p; p += (size_t)D1 * IN_CH * 2;
    unsigned short* wt1r = (unsigned short*)p; p += (size_t)D1 * IN_CH * 2;
    unsigned short* wt2l = (unsigned short*)p; p += (size_t)D2 * D1 * 2;
    unsigned short* wt2r = (unsigned short*)p; p += (size_t)D2 * D1 * 2;
    float* x2 = (float*)p; p += (size_t)N_NODES * D2 * 4;
    int* count      = (int*)p; p += (size_t)N_NODES * 4;
    int* offsets    = (int*)p; p += (size_t)(N_NODES + 4) * 4;
    int* rank       = (int*)p; p += (size_t)ET * 4;
    int* sorted_src = (int*)p; p += (size_t)ET * 4;

    hipMemsetAsync(count, 0, (size_t)N_NODES * sizeof(int), stream);

    prep_kernel<<<XCONV_BLOCKS + WCONV_BLOCKS + HIST_BLOCKS, 256, 0, stream>>>(
        gnn_x, Wl1, Wr1, Wl2, Wr2, edge_dst,
        xb, wt1l, wt1r, wt2l, wt2r, count, rank);
    scan_kernel<<<1, 1024, 0, stream>>>(count, offsets);
    scatter_kernel<<<HIST_BLOCKS, 256, 0, stream>>>(
        edge_src, edge_dst, rank, offsets, sorted_src);

    // layer 1: fused dual GEMM + aggregation
    dim3 g1(M_PAD / 64, D1 / 64);   // (313, 2)
    dual_gemm_mfma_kernel<IN_CH><<<g1, 256, 0, stream>>>(
        xb, wt1l, wt1r, bl1, br1, xl1b, xr1b, N_NODES, D1);
    aggregate1_kernel<<<M_PAD / 4, 256, 0, stream>>>(
        xl1b, xr1b, att1, bias1, offsets, sorted_src, x1b);

    // layer 2
    dim3 g2(M_PAD / 64, D2 / 64);   // (313, 4)
    dual_gemm_mfma_kernel<D1><<<g2, 256, 0, stream>>>(
        x1b, wt2l, wt2r, bl2, br2, xl2b, xr2b, N_NODES, D2);
    aggregate2_kernel<<<(N_NODES + 3) / 4, 256, 0, stream>>>(
        xl2b, xr2b, att2, bias2, offsets, sorted_src, x2);

    // classifier
    classifier_kernel<<<BPAIRS, 256, 0, stream>>>(
        vanilla_x, x2, a1_idx, a2_idx, Wc, bc, out);
}

// Round 6
// 280.704 us; speedup vs baseline: 1.7769x; 1.0632x over previous
//
#include <hip/hip_runtime.h>
#include <math.h>

#define N_NODES 20000
#define M_PAD   20032            // 64-row padded for MFMA row tiles
#define E_EDGES 640000
#define ET (E_EDGES + N_NODES)   // edges + self loops
#define IN_CH 256
#define D1 128                   // H1*C1 = 8*16
#define D2 256                   // H2*C2 = 1*256
#define BPAIRS 4096
#define NEG 0.2f
#define LOG2E 1.4426950408889634f

#define XCONV_BLOCKS 5008        // M_PAD*IN_CH/4/256
#define WCONV_BLOCKS 512         // 131072/256
#define HIST_BLOCKS  ((ET + 255) / 256)
#define MARK_BLOCKS  (2 * BPAIRS / 256)   // 32

#if __has_builtin(__builtin_amdgcn_exp2f)
#define EXP2F(x) __builtin_amdgcn_exp2f(x)
#else
#define EXP2F(x) exp2f(x)
#endif

typedef __bf16 bf16x8 __attribute__((ext_vector_type(8)));
typedef float  f32x4  __attribute__((ext_vector_type(4)));
typedef float  f32x2  __attribute__((ext_vector_type(2)));

__device__ __forceinline__ unsigned short f2b(float f) {
    unsigned int u = __float_as_uint(f);
    unsigned int r = u + 0x7FFFu + ((u >> 16) & 1u);   // RNE
    return (unsigned short)(r >> 16);
}
// packed bf16 pair -> f32x2
__device__ __forceinline__ f32x2 up2(unsigned int u) {
    f32x2 r;
    r.x = __uint_as_float(u << 16);
    r.y = __uint_as_float(u & 0xFFFF0000u);
    return r;
}
__device__ __forceinline__ f32x2 lrelu2(f32x2 s) {
    return __builtin_elementwise_max(s, s * NEG);
}
__device__ __forceinline__ float lrelu(float s) { return fmaxf(s, NEG * s); }

// unpack 8 bf16 (uint4) -> 8 f32
__device__ __forceinline__ void unpack8(uint4 u, float* v) {
    v[0] = __uint_as_float(u.x << 16); v[1] = __uint_as_float(u.x & 0xFFFF0000u);
    v[2] = __uint_as_float(u.y << 16); v[3] = __uint_as_float(u.y & 0xFFFF0000u);
    v[4] = __uint_as_float(u.z << 16); v[5] = __uint_as_float(u.z & 0xFFFF0000u);
    v[6] = __uint_as_float(u.w << 16); v[7] = __uint_as_float(u.w & 0xFFFF0000u);
}

// ------- fused prep: x->bf16, weights->bf16^T, dst histogram, dst-needed mark

__global__ void prep_kernel(
        const float* __restrict__ gnn_x,
        const float* __restrict__ Wl1, const float* __restrict__ Wr1,
        const float* __restrict__ Wl2, const float* __restrict__ Wr2,
        const int* __restrict__ edge_dst,
        const int* __restrict__ a1_raw, const int* __restrict__ a2_raw,
        unsigned short* __restrict__ xb,
        unsigned short* __restrict__ wt1l, unsigned short* __restrict__ wt1r,
        unsigned short* __restrict__ wt2l, unsigned short* __restrict__ wt2r,
        int* __restrict__ count, int* __restrict__ rank,
        int* __restrict__ mark) {
    int bid = blockIdx.x;
    if (bid < XCONV_BLOCKS) {
        int e0 = (bid * 256 + threadIdx.x) * 4;
        int row = e0 >> 8;                 // / IN_CH
        ushort4 o;
        if (row < N_NODES) {
            float4 v = *(const float4*)(gnn_x + e0);
            o.x = f2b(v.x); o.y = f2b(v.y); o.z = f2b(v.z); o.w = f2b(v.w);
        } else {
            o.x = o.y = o.z = o.w = 0;
        }
        *(ushort4*)(xb + e0) = o;
    } else if (bid < XCONV_BLOCKS + WCONV_BLOCKS) {
        int idx = (bid - XCONV_BLOCKS) * 256 + threadIdx.x;  // 0..131071
        int seg = idx >> 15;               // 4 segments of 32768
        int r = idx & 32767;
        const float* W;
        unsigned short* Wt;
        int k, n, K;
        if (seg < 2) {                     // layer1: K=256, N=128
            W = seg ? Wr1 : Wl1; Wt = seg ? wt1r : wt1l;
            k = r >> 7; n = r & 127; K = IN_CH;
        } else {                           // layer2: K=128, N=256
            W = (seg & 1) ? Wr2 : Wl2; Wt = (seg & 1) ? wt2r : wt2l;
            k = r >> 8; n = r & 255; K = D1;
        }
        Wt[n * K + k] = f2b(W[r]);
    } else if (bid < XCONV_BLOCKS + WCONV_BLOCKS + HIST_BLOCKS) {
        int e = (bid - XCONV_BLOCKS - WCONV_BLOCKS) * 256 + threadIdx.x;
        if (e >= ET) return;
        int dst = (e < E_EDGES) ? edge_dst[e] : (e - E_EDGES);
        rank[e] = atomicAdd(&count[dst], 1);
    } else {
        // mark dst nodes needed by the classifier (a1/a2 pair indices)
        int idx = (bid - XCONV_BLOCKS - WCONV_BLOCKS - HIST_BLOCKS) * 256
                + threadIdx.x;             // 0..8191
        __shared__ int stride_s;
        if (threadIdx.x == 0) {
            bool i64 = true;
            for (int i = 1; i < 63; i += 2) i64 = i64 && (a1_raw[i] == 0);
            stride_s = i64 ? 2 : 1;
        }
        __syncthreads();
        int stride = stride_s;
        if (idx < BPAIRS) mark[a1_raw[(long)idx * stride]] = 1;
        else mark[a2_raw[(long)(idx - BPAIRS) * stride]] = 1;
    }
}

// ---------------- CSR scan + scatter ----------------

__global__ __launch_bounds__(1024) void scan_kernel(const int* __restrict__ count,
                                                    int* __restrict__ offsets) {
    const int PER = 20;
    int t = threadIdx.x;
    int base = t * PER;
    int local[PER];
    int sum = 0;
#pragma unroll
    for (int i = 0; i < PER; i++) {
        int idx = base + i;
        int v = (idx < N_NODES) ? count[idx] : 0;
        local[i] = sum;
        sum += v;
    }
    int lane = t & 63, wave = t >> 6;
    int s = sum;
#pragma unroll
    for (int off = 1; off < 64; off <<= 1) {
        int x = __shfl_up(s, off);
        if (lane >= off) s += x;
    }
    __shared__ int wsum[16];
    __shared__ int wpre[16];
    if (lane == 63) wsum[wave] = s;
    __syncthreads();
    if (t == 0) {
        int acc = 0;
        for (int w = 0; w < 16; w++) { wpre[w] = acc; acc += wsum[w]; }
        offsets[N_NODES] = acc;  // == ET
    }
    __syncthreads();
    int thread_excl = wpre[wave] + (s - sum);
#pragma unroll
    for (int i = 0; i < PER; i++) {
        int idx = base + i;
        if (idx < N_NODES) offsets[idx] = thread_excl + local[i];
    }
}

__global__ void scatter_kernel(const int* __restrict__ edge_src,
                               const int* __restrict__ edge_dst,
                               const int* __restrict__ rank,
                               const int* __restrict__ offsets,
                               int* __restrict__ sorted_src) {
    int e = blockIdx.x * blockDim.x + threadIdx.x;
    if (e >= ET) return;
    int dst = (e < E_EDGES) ? edge_dst[e] : (e - E_EDGES);
    int src = (e < E_EDGES) ? edge_src[e] : (e - E_EDGES);
    sorted_src[offsets[dst] + rank[e]] = src;
}

// ---------------- dual MFMA GEMM: Yl = A@Wl^T+bl, Yr = A@Wr^T+br -------------

template <int K>
__global__ __launch_bounds__(256) void dual_gemm_mfma_kernel(
        const unsigned short* __restrict__ A,    // M_PAD x K
        const unsigned short* __restrict__ Wtl,  // NOUT x K
        const unsigned short* __restrict__ Wtr,  // NOUT x K
        const float* __restrict__ bl, const float* __restrict__ br,
        unsigned short* __restrict__ Yl, unsigned short* __restrict__ Yr,
        int M, int NOUT) {
    int wave = threadIdx.x >> 6;
    int lane = threadIdx.x & 63;
    int row0 = blockIdx.x * 64;
    int col0 = (blockIdx.y * 4 + wave) * 16;
    int rsub = lane & 15;
    int koff = (lane >> 4) * 8;

    const unsigned short* ap  = A   + (size_t)(row0 + rsub) * K + koff;
    const unsigned short* bpl = Wtl + (size_t)(col0 + rsub) * K + koff;
    const unsigned short* bpr = Wtr + (size_t)(col0 + rsub) * K + koff;

    f32x4 l0 = {0.f, 0.f, 0.f, 0.f};
    f32x4 l1 = l0, l2 = l0, l3 = l0, r0 = l0, r1 = l0, r2 = l0, r3 = l0;

#pragma unroll
    for (int kb = 0; kb < K; kb += 32) {
        bf16x8 bfl = *(const bf16x8*)(bpl + kb);
        bf16x8 bfr = *(const bf16x8*)(bpr + kb);
        bf16x8 a0 = *(const bf16x8*)(ap + kb);
        bf16x8 a1 = *(const bf16x8*)(ap + 16 * K + kb);
        bf16x8 a2 = *(const bf16x8*)(ap + 32 * K + kb);
        bf16x8 a3 = *(const bf16x8*)(ap + 48 * K + kb);
        l0 = __builtin_amdgcn_mfma_f32_16x16x32_bf16(a0, bfl, l0, 0, 0, 0);
        r0 = __builtin_amdgcn_mfma_f32_16x16x32_bf16(a0, bfr, r0, 0, 0, 0);
        l1 = __builtin_amdgcn_mfma_f32_16x16x32_bf16(a1, bfl, l1, 0, 0, 0);
        r1 = __builtin_amdgcn_mfma_f32_16x16x32_bf16(a1, bfr, r1, 0, 0, 0);
        l2 = __builtin_amdgcn_mfma_f32_16x16x32_bf16(a2, bfl, l2, 0, 0, 0);
        r2 = __builtin_amdgcn_mfma_f32_16x16x32_bf16(a2, bfr, r2, 0, 0, 0);
        l3 = __builtin_amdgcn_mfma_f32_16x16x32_bf16(a3, bfl, l3, 0, 0, 0);
        r3 = __builtin_amdgcn_mfma_f32_16x16x32_bf16(a3, bfr, r3, 0, 0, 0);
    }

    int colg = col0 + rsub;
    float bvl = bl[colg];
    float bvr = br[colg];
    int rbase = row0 + (lane >> 4) * 4;
#pragma unroll
    for (int t = 0; t < 4; t++) {
        f32x4 al = (t == 0) ? l0 : (t == 1) ? l1 : (t == 2) ? l2 : l3;
        f32x4 ar = (t == 0) ? r0 : (t == 1) ? r1 : (t == 2) ? r2 : r3;
#pragma unroll
        for (int r = 0; r < 4; r++) {
            int row = rbase + t * 16 + r;
            if (row < M) {
                Yl[(size_t)row * NOUT + colg] = f2b(al[r] + bvl);
                Yr[(size_t)row * NOUT + colg] = f2b(ar[r] + bvr);
            }
        }
    }
}

// ---------------- layer 1 aggregation ----------------
// 1 wave/dst. QUARTER-wave per edge: q=lane>>4, ql=lane&15 owns 8 ch
// (c0=ql*8, head=ql>>1). 4 edges per wave-instruction. Head reduce =
// shfl_xor 1. Pipelined prefetch. Masked tail.

__global__ __launch_bounds__(256) void aggregate1_kernel(
        const unsigned short* __restrict__ xl1, const unsigned short* __restrict__ xr1,
        const float* __restrict__ att1, const float* __restrict__ bias1,
        const int* __restrict__ offsets, const int* __restrict__ sorted_src,
        unsigned short* __restrict__ x1) {
    int wave = threadIdx.x >> 6;
    int lane = threadIdx.x & 63;
    int q = lane >> 4;                 // quarter 0..3
    int ql = lane & 15;
    int dst = blockIdx.x * 4 + wave;
    if (dst >= M_PAD) return;
    int c0 = ql * 8;
    if (dst >= N_NODES) {              // zero pad rows for the next GEMM
        if (q == 0) {
            uint4 z; z.x = z.y = z.z = z.w = 0;
            *(uint4*)(x1 + (size_t)dst * D1 + c0) = z;
        }
        return;
    }

    uint4 xu = *(const uint4*)(xr1 + (size_t)dst * D1 + c0);
    f32x2 xr[4] = {up2(xu.x), up2(xu.y), up2(xu.z), up2(xu.w)};
    float4 aa0 = *(const float4*)(att1 + c0);
    float4 aa1 = *(const float4*)(att1 + c0 + 4);
    f32x2 att[4];
    att[0].x = aa0.x * LOG2E; att[0].y = aa0.y * LOG2E;
    att[1].x = aa0.z * LOG2E; att[1].y = aa0.w * LOG2E;
    att[2].x = aa1.x * LOG2E; att[2].y = aa1.y * LOG2E;
    att[3].x = aa1.z * LOG2E; att[3].y = aa1.w * LOG2E;

    int beg = offsets[dst], end = offsets[dst + 1];
    const unsigned short* base = xl1 + c0;

    float l = 0.f;
    f32x2 acc[4] = {{0.f,0.f},{0.f,0.f},{0.f,0.f},{0.f,0.f}};

    int i = beg;
    int s0 = sorted_src[min(i + q, end - 1)];
    uint4 g0 = *(const uint4*)(base + (size_t)s0 * D1);
    while (true) {
        int inext = i + 4;
        bool more = inext < end;
        uint4 g1;
        if (more) {
            int s1 = sorted_src[min(inext + q, end - 1)];
            g1 = *(const uint4*)(base + (size_t)s1 * D1);
        }
        bool act = (i + q) < end;
        f32x2 v0 = up2(g0.x), v1 = up2(g0.y), v2 = up2(g0.z), v3 = up2(g0.w);
        f32x2 p2 = att[0] * lrelu2(v0 + xr[0]);
        p2 += att[1] * lrelu2(v1 + xr[1]);
        p2 += att[2] * lrelu2(v2 + xr[2]);
        p2 += att[3] * lrelu2(v3 + xr[3]);
        float p = p2.x + p2.y;
        p += __shfl_xor(p, 1);          // head reduce (2 lanes/head)
        float w = act ? EXP2F(p) : 0.f;
        l += w;
        acc[0] += w * v0; acc[1] += w * v1; acc[2] += w * v2; acc[3] += w * v3;
        if (!more) break;
        i = inext; g0 = g1;
    }
    // merge quarters
    l += __shfl_xor(l, 16);
    l += __shfl_xor(l, 32);
#pragma unroll
    for (int j = 0; j < 4; j++) {
        f32x2 t;
        t.x = __shfl_xor(acc[j].x, 16); t.y = __shfl_xor(acc[j].y, 16);
        acc[j] += t;
        t.x = __shfl_xor(acc[j].x, 32); t.y = __shfl_xor(acc[j].y, 32);
        acc[j] += t;
    }
    if (q == 0) {
        float inv = 1.f / l;
        float4 bb0 = *(const float4*)(bias1 + c0);
        float4 bb1 = *(const float4*)(bias1 + c0 + 4);
        unsigned short o[8];
        o[0] = f2b(fmaxf(acc[0].x * inv + bb0.x, 0.f));
        o[1] = f2b(fmaxf(acc[0].y * inv + bb0.y, 0.f));
        o[2] = f2b(fmaxf(acc[1].x * inv + bb0.z, 0.f));
        o[3] = f2b(fmaxf(acc[1].y * inv + bb0.w, 0.f));
        o[4] = f2b(fmaxf(acc[2].x * inv + bb1.x, 0.f));
        o[5] = f2b(fmaxf(acc[2].y * inv + bb1.y, 0.f));
        o[6] = f2b(fmaxf(acc[3].x * inv + bb1.z, 0.f));
        o[7] = f2b(fmaxf(acc[3].y * inv + bb1.w, 0.f));
        uint4 ov;
        ov.x = (unsigned int)o[0] | ((unsigned int)o[1] << 16);
        ov.y = (unsigned int)o[2] | ((unsigned int)o[3] << 16);
        ov.z = (unsigned int)o[4] | ((unsigned int)o[5] << 16);
        ov.w = (unsigned int)o[6] | ((unsigned int)o[7] << 16);
        *(uint4*)(x1 + (size_t)dst * D1 + c0) = ov;
    }
}

// ---------------- layer 2 aggregation (round-4 body + needed-dst mask) ------
// 1 wave/dst; computed ONLY for dsts the classifier reads (~34% of nodes).

__global__ __launch_bounds__(256) void aggregate2_kernel(
        const unsigned short* __restrict__ xl2, const unsigned short* __restrict__ xr2,
        const float* __restrict__ att2, const float* __restrict__ bias2,
        const int* __restrict__ offsets, const int* __restrict__ sorted_src,
        const int* __restrict__ mark,
        float* __restrict__ x2) {
    int wave = threadIdx.x >> 6;
    int lane = threadIdx.x & 63;
    int half = lane >> 5;
    int hl = lane & 31;
    int dst = blockIdx.x * 4 + wave;
    if (dst >= N_NODES) return;
    if (!mark[dst]) return;            // classifier never reads this row
    int c0 = hl * 8;

    float xr[8], att[8];
    unpack8(*(const uint4*)(xr2 + (size_t)dst * D2 + c0), xr);
#pragma unroll
    for (int j = 0; j < 8; j++) att[j] = att2[c0 + j] * LOG2E;
    int beg = offsets[dst], end = offsets[dst + 1];

    float l = 0.f;
    float acc[8];
#pragma unroll
    for (int j = 0; j < 8; j++) acc[j] = 0.f;

    int i = beg;
    for (; i + 4 <= end; i += 4) {
        int sA = sorted_src[i + half];
        int sB = sorted_src[i + 2 + half];
        float vA[8], vB[8];
        unpack8(*(const uint4*)(xl2 + (size_t)sA * D2 + c0), vA);
        unpack8(*(const uint4*)(xl2 + (size_t)sB * D2 + c0), vB);
        float pA = 0.f, pB = 0.f;
#pragma unroll
        for (int j = 0; j < 8; j++) pA = fmaf(att[j], lrelu(vA[j] + xr[j]), pA);
#pragma unroll
        for (int j = 0; j < 8; j++) pB = fmaf(att[j], lrelu(vB[j] + xr[j]), pB);
        pA += __shfl_xor(pA, 1);  pB += __shfl_xor(pB, 1);
        pA += __shfl_xor(pA, 2);  pB += __shfl_xor(pB, 2);
        pA += __shfl_xor(pA, 4);  pB += __shfl_xor(pB, 4);
        pA += __shfl_xor(pA, 8);  pB += __shfl_xor(pB, 8);
        pA += __shfl_xor(pA, 16); pB += __shfl_xor(pB, 16);
        float wA = EXP2F(pA), wB = EXP2F(pB);
        l += wA + wB;
#pragma unroll
        for (int j = 0; j < 8; j++) acc[j] += wA * vA[j] + wB * vB[j];
    }
    for (; i + 2 <= end; i += 2) {
        int sA = sorted_src[i + half];
        float vA[8];
        unpack8(*(const uint4*)(xl2 + (size_t)sA * D2 + c0), vA);
        float pA = 0.f;
#pragma unroll
        for (int j = 0; j < 8; j++) pA = fmaf(att[j], lrelu(vA[j] + xr[j]), pA);
        pA += __shfl_xor(pA, 1);
        pA += __shfl_xor(pA, 2);
        pA += __shfl_xor(pA, 4);
        pA += __shfl_xor(pA, 8);
        pA += __shfl_xor(pA, 16);
        float wA = EXP2F(pA);
        l += wA;
#pragma unroll
        for (int j = 0; j < 8; j++) acc[j] += wA * vA[j];
    }
    if (i < end && half == 0) {
        int sA = sorted_src[i];
        float vA[8];
        unpack8(*(const uint4*)(xl2 + (size_t)sA * D2 + c0), vA);
        float pA = 0.f;
#pragma unroll
        for (int j = 0; j < 8; j++) pA = fmaf(att[j], lrelu(vA[j] + xr[j]), pA);
        pA += __shfl_xor(pA, 1);
        pA += __shfl_xor(pA, 2);
        pA += __shfl_xor(pA, 4);
        pA += __shfl_xor(pA, 8);
        pA += __shfl_xor(pA, 16);
        float wA = EXP2F(pA);
        l += wA;
#pragma unroll
        for (int j = 0; j < 8; j++) acc[j] += wA * vA[j];
    }
    // merge halves
    l += __shfl_xor(l, 32);
#pragma unroll
    for (int j = 0; j < 8; j++) acc[j] += __shfl_xor(acc[j], 32);
    if (half == 0) {
        float inv = 1.f / l;
        float4 o0, o1;
        o0.x = acc[0] * inv + bias2[c0 + 0];
        o0.y = acc[1] * inv + bias2[c0 + 1];
        o0.z = acc[2] * inv + bias2[c0 + 2];
        o0.w = acc[3] * inv + bias2[c0 + 3];
        o1.x = acc[4] * inv + bias2[c0 + 4];
        o1.y = acc[5] * inv + bias2[c0 + 5];
        o1.z = acc[6] * inv + bias2[c0 + 6];
        o1.w = acc[7] * inv + bias2[c0 + 7];
        *(float4*)(x2 + (size_t)dst * D2 + c0) = o0;
        *(float4*)(x2 + (size_t)dst * D2 + c0 + 4) = o1;
    }
}

// ---------------- classifier ----------------

__global__ __launch_bounds__(256) void classifier_kernel(
        const float* __restrict__ vanilla_x, const float* __restrict__ x2,
        const int* __restrict__ a1_raw, const int* __restrict__ a2_raw,
        const float* __restrict__ Wc, const float* __restrict__ bc,
        float* __restrict__ out) {
    int b = blockIdx.x;
    int t = threadIdx.x;

    // detect int64 vs int32 storage of index arrays
    __shared__ int stride_s;
    if (t == 0) {
        bool i64 = true;
        for (int i = 1; i < 63; i += 2) i64 = i64 && (a1_raw[i] == 0);
        stride_s = i64 ? 2 : 1;
    }
    __syncthreads();
    int stride = stride_s;
    int a1 = a1_raw[(long)b * stride];
    int a2 = a2_raw[(long)b * stride];

    float s = vanilla_x[a1 * IN_CH + t] * Wc[t]
            + vanilla_x[a2 * IN_CH + t] * Wc[IN_CH + t]
            + x2[a1 * D2 + t] * Wc[2 * IN_CH + t]
            + x2[a2 * D2 + t] * Wc[3 * IN_CH + t];
    s += __shfl_xor(s, 1);
    s += __shfl_xor(s, 2);
    s += __shfl_xor(s, 4);
    s += __shfl_xor(s, 8);
    s += __shfl_xor(s, 16);
    s += __shfl_xor(s, 32);
    __shared__ float part[4];
    if ((t & 63) == 0) part[t >> 6] = s;
    __syncthreads();
    if (t == 0) out[b] = part[0] + part[1] + part[2] + part[3] + bc[0];
}

// ---------------- launch ----------------

extern "C" void kernel_launch(void* const* d_in, const int* in_sizes, int n_in,
                              void* d_out, int out_size, void* d_ws, size_t ws_size,
                              hipStream_t stream) {
    const float* gnn_x     = (const float*)d_in[0];
    const float* vanilla_x = (const float*)d_in[1];
    const int*   edge_src  = (const int*)d_in[2];
    const int*   edge_dst  = (const int*)d_in[3];
    const int*   a1_idx    = (const int*)d_in[4];
    const int*   a2_idx    = (const int*)d_in[5];
    const float* Wl1   = (const float*)d_in[6];
    const float* bl1   = (const float*)d_in[7];
    const float* Wr1   = (const float*)d_in[8];
    const float* br1   = (const float*)d_in[9];
    const float* att1  = (const float*)d_in[10];
    const float* bias1 = (const float*)d_in[11];
    const float* Wl2   = (const float*)d_in[12];
    const float* bl2   = (const float*)d_in[13];
    const float* Wr2   = (const float*)d_in[14];
    const float* br2   = (const float*)d_in[15];
    const float* att2  = (const float*)d_in[16];
    const float* bias2 = (const float*)d_in[17];
    const float* Wc    = (const float*)d_in[18];
    const float* bc    = (const float*)d_in[19];
    float* out = (float*)d_out;

    // workspace layout
    char* p = (char*)d_ws;
    unsigned short* xb   = (unsigned short*)p; p += (size_t)M_PAD * IN_CH * 2;
    unsigned short* x1b  = (unsigned short*)p; p += (size_t)M_PAD * D1 * 2;
    unsigned short* xl1b = (unsigned short*)p; p += (size_t)N_NODES * D1 * 2;
    unsigned short* xr1b = (unsigned short*)p; p += (size_t)N_NODES * D1 * 2;
    unsigned short* xl2b = (unsigned short*)p; p += (size_t)N_NODES * D2 * 2;
    unsigned short* xr2b = (unsigned short*)p; p += (size_t)N_NODES * D2 * 2;
    unsigned short* wt1l = (unsigned short*)p; p += (size_t)D1 * IN_CH * 2;
    unsigned short* wt1r = (unsigned short*)p; p += (size_t)D1 * IN_CH * 2;
    unsigned short* wt2l = (unsigned short*)p; p += (size_t)D2 * D1 * 2;
    unsigned short* wt2r = (unsigned short*)p; p += (size_t)D2 * D1 * 2;
    float* x2 = (float*)p; p += (size_t)N_NODES * D2 * 4;
    int* count      = (int*)p; p += (size_t)N_NODES * 4;
    int* mark       = (int*)p; p += (size_t)N_NODES * 4;
    int* offsets    = (int*)p; p += (size_t)(N_NODES + 4) * 4;
    int* rank       = (int*)p; p += (size_t)ET * 4;
    int* sorted_src = (int*)p; p += (size_t)ET * 4;

    // zero count AND mark in one memset (they are adjacent)
    hipMemsetAsync(count, 0, (size_t)2 * N_NODES * sizeof(int), stream);

    prep_kernel<<<XCONV_BLOCKS + WCONV_BLOCKS + HIST_BLOCKS + MARK_BLOCKS,
                  256, 0, stream>>>(
        gnn_x, Wl1, Wr1, Wl2, Wr2, edge_dst, a1_idx, a2_idx,
        xb, wt1l, wt1r, wt2l, wt2r, count, rank, mark);
    scan_kernel<<<1, 1024, 0, stream>>>(count, offsets);
    scatter_kernel<<<HIST_BLOCKS, 256, 0, stream>>>(
        edge_src, edge_dst, rank, offsets, sorted_src);

    // layer 1: fused dual GEMM + aggregation
    dim3 g1(M_PAD / 64, D1 / 64);   // (313, 2)
    dual_gemm_mfma_kernel<IN_CH><<<g1, 256, 0, stream>>>(
        xb, wt1l, wt1r, bl1, br1, xl1b, xr1b, N_NODES, D1);
    aggregate1_kernel<<<M_PAD / 4, 256, 0, stream>>>(
        xl1b, xr1b, att1, bias1, offsets, sorted_src, x1b);

    // layer 2
    dim3 g2(M_PAD / 64, D2 / 64);   // (313, 4)
    dual_gemm_mfma_kernel<D1><<<g2, 256, 0, stream>>>(
        x1b, wt2l, wt2r, bl2, br2, xl2b, xr2b, N_NODES, D2);
    aggregate2_kernel<<<(N_NODES + 3) / 4, 256, 0, stream>>>(
        xl2b, xr2b, att2, bias2, offsets, sorted_src, mark, x2);

    // classifier
    classifier_kernel<<<BPAIRS, 256, 0, stream>>>(
        vanilla_x, x2, a1_idx, a2_idx, Wc, bc, out);
}